// Round 5
// baseline (1252.778 us; speedup 1.0000x reference)
//
#include <hip/hip_runtime.h>

#define NBATCH 4
#define NNODE  10000
#define MTOT   40000
#define NEDGE  160000
#define NFEAT  57
#define RTDIM  78
#define XROW   291
#define SLOPE  0.2f
#define BNEPS  1e-5f

// ---- workspace layout (float element offsets) ----
#define OFF_HN   ((size_t)0)                         // MTOT*64
#define OFF_XW   ((size_t)MTOT*64)                   // MTOT*256
#define OFF_H2   (OFF_XW + (size_t)MTOT*256)         // MTOT*256
#define OFF_ASRC (OFF_H2 + (size_t)MTOT*256)         // MTOT*4
#define OFF_ADST (OFF_ASRC + (size_t)MTOT*4)
#define OFF_EMAX (OFF_ADST + (size_t)MTOT*4)
#define OFF_DEN  (OFF_EMAX + (size_t)MTOT*4)
#define OFF_STAT (OFF_DEN + (size_t)MTOT*4)          // 1024: sum1,sq1,sum2,sq2
#define OFF_AFF  (OFF_STAT + 1024)                   // a1,b1s,a2,b2s,wcp,bias0
#define OFF_INT  (OFF_AFF + 5*256 + 16)              // ints: cnt NN, fill NN, ptr NN+1, csr E

__device__ __forceinline__ float lrelu(float x){ return x > 0.f ? x : SLOPE*x; }
// fast sigmoid/tanh via v_exp_f32. tanh clamped so __expf never returns inf (no inf/inf NaN).
__device__ __forceinline__ float fsig(float x){ return __fdividef(1.f, 1.f + __expf(-x)); }
__device__ __forceinline__ float ftanh(float x){
  x = fminf(fmaxf(x, -15.f), 15.f);
  float t = __expf(2.f*x);
  return __fdividef(t - 1.f, t + 1.f);
}

// ------------------------- utility kernels -------------------------
__global__ __launch_bounds__(256) void k_zero(float* __restrict__ p, int n){
  int i = blockIdx.x*256 + threadIdx.x;
  if (i < n) p[i] = 0.f;
}

__global__ __launch_bounds__(256) void k_count(const int* __restrict__ dst, int* __restrict__ cnt){
  int e = blockIdx.x*256 + threadIdx.x;
  if (e < NEDGE) atomicAdd(&cnt[dst[e]], 1);
}

__global__ __launch_bounds__(1024) void k_scan(const int* __restrict__ cnt, int* __restrict__ ptr){
  __shared__ int sd[1024];
  int t = threadIdx.x;
  int loc[10]; int tot = 0;
  #pragma unroll
  for (int i=0;i<10;i++){
    int idx = t*10 + i;
    int v = (idx < NNODE) ? cnt[idx] : 0;
    loc[i] = tot; tot += v;
  }
  sd[t] = tot;
  __syncthreads();
  for (int off=1; off<1024; off<<=1){
    int v = (t >= off) ? sd[t-off] : 0;
    __syncthreads();
    sd[t] += v;
    __syncthreads();
  }
  int excl = sd[t] - tot;
  #pragma unroll
  for (int i=0;i<10;i++){
    int idx = t*10 + i;
    if (idx < NNODE) ptr[idx] = excl + loc[i];
  }
  if (t == 1023) ptr[NNODE] = sd[1023];
}

__global__ __launch_bounds__(256) void k_fill(const int* __restrict__ dst, const int* __restrict__ ptr,
                                              int* __restrict__ fil, int* __restrict__ csr){
  int e = blockIdx.x*256 + threadIdx.x;
  if (e >= NEDGE) return;
  int d = dst[e];
  int pos = ptr[d] + atomicAdd(&fil[d], 1);
  csr[pos] = e;
}

// ------------------------- fused LSTM + temporal attention + static branch -------------------------
// block: 256 threads = 4 waves, 32 nodes/block. lane j = hidden idx; wave grp owns 8 nodes.
// __launch_bounds__(256,4): force VGPR<=128 -> 4 blocks/CU (16 waves) to hide staging latency.
__global__ __launch_bounds__(256, 4) void k_lstm(
    const float* __restrict__ x,
    const float* __restrict__ Wih, const float* __restrict__ Whh,
    const float* __restrict__ bih, const float* __restrict__ bhh,
    const float* __restrict__ Wa,
    const float* __restrict__ Wn, const float* __restrict__ bnb,
    float* __restrict__ hnode)
{
  __shared__ float Xs[32][80];
  __shared__ float Hs[32][64];
  __shared__ float WcL[256][20];
  const int tid = threadIdx.x;
  const int j   = tid & 63;
  const int grp = tid >> 6;
  const int mb  = blockIdx.x * 32;

  const float bg0 = bih[j]     + bhh[j];
  const float bg1 = bih[64+j]  + bhh[64+j];
  const float bg2 = bih[128+j] + bhh[128+j];
  const float bg3 = bih[192+j] + bhh[192+j];

  float c[8]; float ht0[8], ht1[8], ht2[8];
  #pragma unroll
  for (int i=0;i<8;i++) c[i] = 0.f;

  #pragma unroll
  for (int t=0; t<3; ++t) {
    __syncthreads();
    for (int idx = tid; idx < 32*80; idx += 256) {
      int node = idx / 80, k = idx - node*80;
      Xs[node][k] = (k < RTDIM) ? x[(size_t)(mb+node)*XROW + NFEAT + t*RTDIM + k] : 0.f;
    }
    float a0[8],a1[8],a2[8],a3[8];
    #pragma unroll
    for (int i=0;i<8;i++){a0[i]=0.f;a1[i]=0.f;a2[i]=0.f;a3[i]=0.f;}

    // ---- Wih phase: k = 0..79 (padded) ----
    for (int kc=0; kc<80; kc+=16) {
      __syncthreads();
      {
        int g0 = tid >> 2, q = tid & 3;
        #pragma unroll
        for (int gp=0; gp<4; ++gp) {
          int gate = g0 + gp*64;
          int k0 = kc + q*4;
          float4 v;
          v.x = (k0+0 < RTDIM) ? Wih[gate*RTDIM + k0+0] : 0.f;
          v.y = (k0+1 < RTDIM) ? Wih[gate*RTDIM + k0+1] : 0.f;
          v.z = (k0+2 < RTDIM) ? Wih[gate*RTDIM + k0+2] : 0.f;
          v.w = (k0+3 < RTDIM) ? Wih[gate*RTDIM + k0+3] : 0.f;
          *(float4*)&WcL[gate][q*4] = v;
        }
      }
      __syncthreads();
      #pragma unroll
      for (int k4=0;k4<4;++k4){
        const float4 w0 = *(const float4*)&WcL[j][k4*4];
        const float4 w1 = *(const float4*)&WcL[64+j][k4*4];
        const float4 w2 = *(const float4*)&WcL[128+j][k4*4];
        const float4 w3 = *(const float4*)&WcL[192+j][k4*4];
        #pragma unroll
        for (int i=0;i<8;++i){
          const float4 xv = *(const float4*)&Xs[grp*8+i][kc + k4*4];
          a0[i]=fmaf(w0.x,xv.x,a0[i]); a0[i]=fmaf(w0.y,xv.y,a0[i]); a0[i]=fmaf(w0.z,xv.z,a0[i]); a0[i]=fmaf(w0.w,xv.w,a0[i]);
          a1[i]=fmaf(w1.x,xv.x,a1[i]); a1[i]=fmaf(w1.y,xv.y,a1[i]); a1[i]=fmaf(w1.z,xv.z,a1[i]); a1[i]=fmaf(w1.w,xv.w,a1[i]);
          a2[i]=fmaf(w2.x,xv.x,a2[i]); a2[i]=fmaf(w2.y,xv.y,a2[i]); a2[i]=fmaf(w2.z,xv.z,a2[i]); a2[i]=fmaf(w2.w,xv.w,a2[i]);
          a3[i]=fmaf(w3.x,xv.x,a3[i]); a3[i]=fmaf(w3.y,xv.y,a3[i]); a3[i]=fmaf(w3.z,xv.z,a3[i]); a3[i]=fmaf(w3.w,xv.w,a3[i]);
        }
      }
    }
    // ---- Whh phase (skip at t=0, h0 == 0) ----
    if (t > 0) {
      for (int kc=0; kc<64; kc+=16) {
        __syncthreads();
        {
          int g0 = tid >> 2, q = tid & 3;
          #pragma unroll
          for (int gp=0; gp<4; ++gp) {
            int gate = g0 + gp*64;
            *(float4*)&WcL[gate][q*4] = *(const float4*)&Whh[gate*64 + kc + q*4];
          }
        }
        __syncthreads();
        #pragma unroll
        for (int k4=0;k4<4;++k4){
          const float4 w0 = *(const float4*)&WcL[j][k4*4];
          const float4 w1 = *(const float4*)&WcL[64+j][k4*4];
          const float4 w2 = *(const float4*)&WcL[128+j][k4*4];
          const float4 w3 = *(const float4*)&WcL[192+j][k4*4];
          #pragma unroll
          for (int i=0;i<8;++i){
            const float4 xv = *(const float4*)&Hs[grp*8+i][kc + k4*4];
            a0[i]=fmaf(w0.x,xv.x,a0[i]); a0[i]=fmaf(w0.y,xv.y,a0[i]); a0[i]=fmaf(w0.z,xv.z,a0[i]); a0[i]=fmaf(w0.w,xv.w,a0[i]);
            a1[i]=fmaf(w1.x,xv.x,a1[i]); a1[i]=fmaf(w1.y,xv.y,a1[i]); a1[i]=fmaf(w1.z,xv.z,a1[i]); a1[i]=fmaf(w1.w,xv.w,a1[i]);
            a2[i]=fmaf(w2.x,xv.x,a2[i]); a2[i]=fmaf(w2.y,xv.y,a2[i]); a2[i]=fmaf(w2.z,xv.z,a2[i]); a2[i]=fmaf(w2.w,xv.w,a2[i]);
            a3[i]=fmaf(w3.x,xv.x,a3[i]); a3[i]=fmaf(w3.y,xv.y,a3[i]); a3[i]=fmaf(w3.z,xv.z,a3[i]); a3[i]=fmaf(w3.w,xv.w,a3[i]);
          }
        }
      }
    }
    __syncthreads();  // all Hs reads done before overwrite
    #pragma unroll
    for (int i=0;i<8;++i){
      float iv = fsig(a0[i]+bg0);
      float fv = fsig(a1[i]+bg1);
      float gv = ftanh(a2[i]+bg2);
      float ov = fsig(a3[i]+bg3);
      float cc = fv*c[i] + iv*gv;
      c[i] = cc;
      float hv = ov * ftanh(cc);
      if (t == 0) ht0[i] = hv;
      else if (t == 1) ht1[i] = hv;
      else ht2[i] = hv;
      if (t < 2) Hs[grp*8+i][j] = hv;
    }
  }

  // ---- temporal attention (softmax over T; ba cancels) ----
  const float wa = Wa[j];
  float htemp[8];
  #pragma unroll
  for (int i=0;i<8;++i){
    float s0 = ht0[i]*wa, s1 = ht1[i]*wa, s2 = ht2[i]*wa;
    #pragma unroll
    for (int off=32; off; off>>=1){
      s0 += __shfl_xor(s0, off);
      s1 += __shfl_xor(s1, off);
      s2 += __shfl_xor(s2, off);
    }
    float mx = fmaxf(s0, fmaxf(s1, s2));
    float e0 = __expf(s0-mx), e1 = __expf(s1-mx), e2 = __expf(s2-mx);
    float inv = __fdividef(1.f, e0+e1+e2);
    htemp[i] = (e0*ht0[i] + e1*ht1[i] + e2*ht2[i]) * inv;
  }

  // ---- static branch: relu(node_f @ Wn^T + bnb) ----
  __syncthreads();
  for (int idx = tid; idx < 32*64; idx += 256){
    int node = idx >> 6, k = idx & 63;
    Xs[node][k] = (k < NFEAT) ? x[(size_t)(mb+node)*XROW + k] : 0.f;
  }
  float as_[8];
  #pragma unroll
  for (int i=0;i<8;++i) as_[i]=0.f;
  for (int kc=0; kc<64; kc+=16){
    __syncthreads();
    {
      int g0 = tid >> 2, q = tid & 3;   // 64 gates in one pass
      int k0 = kc + q*4;
      float4 v;
      v.x = (k0+0 < NFEAT) ? Wn[g0*NFEAT + k0+0] : 0.f;
      v.y = (k0+1 < NFEAT) ? Wn[g0*NFEAT + k0+1] : 0.f;
      v.z = (k0+2 < NFEAT) ? Wn[g0*NFEAT + k0+2] : 0.f;
      v.w = (k0+3 < NFEAT) ? Wn[g0*NFEAT + k0+3] : 0.f;
      *(float4*)&WcL[g0][q*4] = v;
    }
    __syncthreads();
    #pragma unroll
    for (int k4=0;k4<4;++k4){
      const float4 w = *(const float4*)&WcL[j][k4*4];
      #pragma unroll
      for (int i=0;i<8;++i){
        const float4 xv = *(const float4*)&Xs[grp*8+i][kc + k4*4];
        as_[i]=fmaf(w.x,xv.x,as_[i]); as_[i]=fmaf(w.y,xv.y,as_[i]);
        as_[i]=fmaf(w.z,xv.z,as_[i]); as_[i]=fmaf(w.w,xv.w,as_[i]);
      }
    }
  }
  const float bn = bnb[j];
  #pragma unroll
  for (int i=0;i<8;++i){
    float hs = as_[i] + bn; hs = hs > 0.f ? hs : 0.f;
    hnode[(size_t)(mb+grp*8+i)*64 + j] = htemp[i] + hs;
  }
}

// ------------------------- xw = in @ W^T (+BN affine on load) + fused asrc/adst -------------------------
template<int K, bool AFF>
__global__ __launch_bounds__(256, 4) void k_xw(
    const float* __restrict__ in, const float* __restrict__ W,
    const float* __restrict__ avs, const float* __restrict__ avd,
    const float* __restrict__ affA, const float* __restrict__ affB,
    float* __restrict__ XW, float* __restrict__ asrc, float* __restrict__ adst)
{
  __shared__ float Xs[32][K];
  __shared__ float WcL[256][20];
  const int tid = threadIdx.x;
  const int j   = tid & 63;
  const int grp = tid >> 6;
  const int mb  = blockIdx.x * 32;

  if constexpr (K == 256) {
    float sA = AFF ? affA[tid] : 1.f;
    float sB = AFF ? affB[tid] : 0.f;
    for (int node=0; node<32; ++node){
      float v = in[(size_t)(mb+node)*K + tid];
      Xs[node][tid] = v*sA + sB;
    }
  } else {
    for (int idx = tid; idx < 32*K; idx += 256){
      int node = idx / K, k = idx - node*K;
      Xs[node][k] = in[(size_t)(mb+node)*K + k];
    }
  }

  float a0[8],a1[8],a2[8],a3[8];
  #pragma unroll
  for (int i=0;i<8;i++){a0[i]=0.f;a1[i]=0.f;a2[i]=0.f;a3[i]=0.f;}

  for (int kc=0; kc<K; kc+=16){
    __syncthreads();
    {
      int g0 = tid >> 2, q = tid & 3;
      #pragma unroll
      for (int gp=0;gp<4;++gp){
        int gate = g0 + gp*64;
        *(float4*)&WcL[gate][q*4] = *(const float4*)&W[(size_t)gate*K + kc + q*4];
      }
    }
    __syncthreads();
    #pragma unroll
    for (int k4=0;k4<4;++k4){
      const float4 w0 = *(const float4*)&WcL[j][k4*4];
      const float4 w1 = *(const float4*)&WcL[64+j][k4*4];
      const float4 w2 = *(const float4*)&WcL[128+j][k4*4];
      const float4 w3 = *(const float4*)&WcL[192+j][k4*4];
      #pragma unroll
      for (int i=0;i<8;++i){
        const float4 xv = *(const float4*)&Xs[grp*8+i][kc + k4*4];
        a0[i]=fmaf(w0.x,xv.x,a0[i]); a0[i]=fmaf(w0.y,xv.y,a0[i]); a0[i]=fmaf(w0.z,xv.z,a0[i]); a0[i]=fmaf(w0.w,xv.w,a0[i]);
        a1[i]=fmaf(w1.x,xv.x,a1[i]); a1[i]=fmaf(w1.y,xv.y,a1[i]); a1[i]=fmaf(w1.z,xv.z,a1[i]); a1[i]=fmaf(w1.w,xv.w,a1[i]);
        a2[i]=fmaf(w2.x,xv.x,a2[i]); a2[i]=fmaf(w2.y,xv.y,a2[i]); a2[i]=fmaf(w2.z,xv.z,a2[i]); a2[i]=fmaf(w2.w,xv.w,a2[i]);
        a3[i]=fmaf(w3.x,xv.x,a3[i]); a3[i]=fmaf(w3.y,xv.y,a3[i]); a3[i]=fmaf(w3.z,xv.z,a3[i]); a3[i]=fmaf(w3.w,xv.w,a3[i]);
      }
    }
  }

  #pragma unroll
  for (int i=0;i<8;++i){
    size_t base = (size_t)(mb+grp*8+i)*256;
    XW[base + j]       = a0[i];
    XW[base + 64 + j]  = a1[i];
    XW[base + 128 + j] = a2[i];
    XW[base + 192 + j] = a3[i];
  }
  const float s0w = avs[j], s1w = avs[64+j], s2w = avs[128+j], s3w = avs[192+j];
  const float d0w = avd[j], d1w = avd[64+j], d2w = avd[128+j], d3w = avd[192+j];
  #pragma unroll
  for (int i=0;i<8;++i){
    float ps0=a0[i]*s0w, ps1=a1[i]*s1w, ps2=a2[i]*s2w, ps3=a3[i]*s3w;
    float pd0=a0[i]*d0w, pd1=a1[i]*d1w, pd2=a2[i]*d2w, pd3=a3[i]*d3w;
    #pragma unroll
    for (int off=32; off; off>>=1){
      ps0 += __shfl_xor(ps0, off); ps1 += __shfl_xor(ps1, off);
      ps2 += __shfl_xor(ps2, off); ps3 += __shfl_xor(ps3, off);
      pd0 += __shfl_xor(pd0, off); pd1 += __shfl_xor(pd1, off);
      pd2 += __shfl_xor(pd2, off); pd3 += __shfl_xor(pd3, off);
    }
    if (j == 0){
      int m = mb + grp*8 + i;
      asrc[m*4+0]=ps0; asrc[m*4+1]=ps1; asrc[m*4+2]=ps2; asrc[m*4+3]=ps3;
      adst[m*4+0]=pd0; adst[m*4+1]=pd1; adst[m*4+2]=pd2; adst[m*4+3]=pd3;
    }
  }
}

// ------------------------- per-dst softmax stats (max & denom incl. self loop) -------------------------
__global__ __launch_bounds__(256) void k_stats(
    const float* __restrict__ asrc, const float* __restrict__ adst,
    const int* __restrict__ esrc, const int* __restrict__ csr, const int* __restrict__ ptr,
    float* __restrict__ emax, float* __restrict__ den)
{
  const int m = blockIdx.x*4 + (threadIdx.x>>6);
  const int lane = threadIdx.x & 63;
  const int n = m % NNODE;
  const int bb = m / NNODE;
  const int s0 = ptr[n], s1 = ptr[n+1];
  const float4 ad  = *(const float4*)&adst[(size_t)m*4];
  const float4 asf = *(const float4*)&asrc[(size_t)m*4];
  const float ex0 = lrelu(asf.x+ad.x), ex1 = lrelu(asf.y+ad.y);
  const float ex2 = lrelu(asf.z+ad.z), ex3 = lrelu(asf.w+ad.w);
  float m0=ex0, m1=ex1, m2=ex2, m3=ex3;
  for (int e = s0+lane; e < s1; e += 64){
    int src = esrc[csr[e]];
    const float4 av = *(const float4*)&asrc[(size_t)(bb*NNODE+src)*4];
    m0 = fmaxf(m0, lrelu(av.x+ad.x));
    m1 = fmaxf(m1, lrelu(av.y+ad.y));
    m2 = fmaxf(m2, lrelu(av.z+ad.z));
    m3 = fmaxf(m3, lrelu(av.w+ad.w));
  }
  #pragma unroll
  for (int off=32; off; off>>=1){
    m0 = fmaxf(m0, __shfl_xor(m0, off));
    m1 = fmaxf(m1, __shfl_xor(m1, off));
    m2 = fmaxf(m2, __shfl_xor(m2, off));
    m3 = fmaxf(m3, __shfl_xor(m3, off));
  }
  float d0=0.f,d1=0.f,d2=0.f,d3=0.f;
  for (int e = s0+lane; e < s1; e += 64){
    int src = esrc[csr[e]];
    const float4 av = *(const float4*)&asrc[(size_t)(bb*NNODE+src)*4];
    d0 += __expf(lrelu(av.x+ad.x) - m0);
    d1 += __expf(lrelu(av.y+ad.y) - m1);
    d2 += __expf(lrelu(av.z+ad.z) - m2);
    d3 += __expf(lrelu(av.w+ad.w) - m3);
  }
  #pragma unroll
  for (int off=32; off; off>>=1){
    d0 += __shfl_xor(d0, off); d1 += __shfl_xor(d1, off);
    d2 += __shfl_xor(d2, off); d3 += __shfl_xor(d3, off);
  }
  d0 += __expf(ex0 - m0); d1 += __expf(ex1 - m1);
  d2 += __expf(ex2 - m2); d3 += __expf(ex3 - m3);
  if (lane == 0){
    float4 mv = {m0,m1,m2,m3}; *(float4*)&emax[(size_t)m*4] = mv;
    float4 dv = {d0,d1,d2,d3}; *(float4*)&den[(size_t)m*4]  = dv;
  }
}

// ------------------------- per-dst weighted aggregation + bias + relu -------------------------
__global__ __launch_bounds__(256) void k_agg(
    const float* __restrict__ XW, const float* __restrict__ asrc, const float* __restrict__ adst,
    const float* __restrict__ emax, const float* __restrict__ den,
    const int* __restrict__ esrc, const int* __restrict__ csr, const int* __restrict__ ptr,
    const float* __restrict__ bias, float* __restrict__ out)
{
  const int m = blockIdx.x*4 + (threadIdx.x>>6);
  const int lane = threadIdx.x & 63;
  const int h = lane >> 4;
  const int n = m % NNODE;
  const int bb = m / NNODE;
  const float adh  = adst[(size_t)m*4 + h];
  const float mxh  = emax[(size_t)m*4 + h];
  const float invd = __fdividef(1.f, den[(size_t)m*4 + h] + 1e-16f);
  float al = __expf(lrelu(asrc[(size_t)m*4+h] + adh) - mxh) * invd;
  float4 xv = *(const float4*)&XW[(size_t)m*256 + lane*4];
  float acx = al*xv.x, acy = al*xv.y, acz = al*xv.z, acw = al*xv.w;
  const int s0 = ptr[n], s1 = ptr[n+1];
  for (int e = s0; e < s1; ++e){
    int src = esrc[csr[e]];
    int ms = bb*NNODE + src;
    float a2 = __expf(lrelu(asrc[(size_t)ms*4+h] + adh) - mxh) * invd;
    float4 x2 = *(const float4*)&XW[(size_t)ms*256 + lane*4];
    acx = fmaf(a2, x2.x, acx); acy = fmaf(a2, x2.y, acy);
    acz = fmaf(a2, x2.z, acz); acw = fmaf(a2, x2.w, acw);
  }
  const float4 bv = *(const float4*)&bias[lane*4];
  acx = fmaxf(acx+bv.x, 0.f); acy = fmaxf(acy+bv.y, 0.f);
  acz = fmaxf(acz+bv.z, 0.f); acw = fmaxf(acw+bv.w, 0.f);
  float4 o = {acx,acy,acz,acw};
  *(float4*)&out[(size_t)m*256 + lane*4] = o;
}

// ------------------------- batchnorm -------------------------
__global__ __launch_bounds__(256) void k_bnstats(const float* __restrict__ H,
                                                 float* __restrict__ sum, float* __restrict__ sq){
  int c = threadIdx.x;
  float s = 0.f, q = 0.f;
  for (int r = blockIdx.x; r < MTOT; r += gridDim.x){
    float v = H[(size_t)r*256 + c];
    s += v; q += v*v;
  }
  atomicAdd(&sum[c], s);
  atomicAdd(&sq[c],  q);
}

__global__ __launch_bounds__(256) void k_bnfin(const float* __restrict__ sum, const float* __restrict__ sq,
    const float* __restrict__ g, const float* __restrict__ be,
    float* __restrict__ a, float* __restrict__ bsh)
{
  int c = threadIdx.x;
  float mean = sum[c] * (1.f/MTOT);
  float var  = sq[c]  * (1.f/MTOT) - mean*mean;
  float rstd = rsqrtf(var + BNEPS);
  float av = g[c] * rstd;
  a[c]   = av;
  bsh[c] = be[c] - mean*av;
}

__global__ __launch_bounds__(256) void k_fold(const float* __restrict__ a2, const float* __restrict__ b2s,
    const float* __restrict__ Wcw, const float* __restrict__ bc,
    float* __restrict__ wcp, float* __restrict__ bias0)
{
  __shared__ float red[256];
  int c = threadIdx.x;
  float w = Wcw[c];
  wcp[c] = a2[c]*w;
  red[c] = b2s[c]*w;
  __syncthreads();
  for (int off=128; off; off>>=1){
    if (c < off) red[c] += red[c+off];
    __syncthreads();
  }
  if (c == 0) bias0[0] = red[0] + bc[0];
}

// ------------------------- final projection -------------------------
__global__ __launch_bounds__(256) void k_out(const float* __restrict__ H, const float* __restrict__ wcp,
    const float* __restrict__ bias0, float* __restrict__ out)
{
  const int m = blockIdx.x*4 + (threadIdx.x>>6);
  const int lane = threadIdx.x & 63;
  const float4 h4 = *(const float4*)&H[(size_t)m*256 + lane*4];
  const float4 w4 = *(const float4*)&wcp[lane*4];
  float p = h4.x*w4.x + h4.y*w4.y + h4.z*w4.z + h4.w*w4.w;
  #pragma unroll
  for (int off=32; off; off>>=1) p += __shfl_xor(p, off);
  if (lane == 0) out[m] = p + bias0[0];
}

// ------------------------- launch -------------------------
extern "C" void kernel_launch(void* const* d_in, const int* in_sizes, int n_in,
                              void* d_out, int out_size, void* d_ws, size_t ws_size,
                              hipStream_t stream)
{
  const float* x    = (const float*)d_in[0];
  const int*   ei   = (const int*)d_in[1];
  const float* Wih  = (const float*)d_in[2];
  const float* Whh  = (const float*)d_in[3];
  const float* bih  = (const float*)d_in[4];
  const float* bhh  = (const float*)d_in[5];
  const float* Wa   = (const float*)d_in[6];
  const float* Wn   = (const float*)d_in[8];
  const float* bnb  = (const float*)d_in[9];
  const float* W1   = (const float*)d_in[10];
  const float* as1  = (const float*)d_in[11];
  const float* ad1  = (const float*)d_in[12];
  const float* b1   = (const float*)d_in[13];
  const float* W2   = (const float*)d_in[14];
  const float* as2  = (const float*)d_in[15];
  const float* ad2  = (const float*)d_in[16];
  const float* b2   = (const float*)d_in[17];
  const float* g1   = (const float*)d_in[18];
  const float* be1  = (const float*)d_in[19];
  const float* g2   = (const float*)d_in[20];
  const float* be2  = (const float*)d_in[21];
  const float* Wcw  = (const float*)d_in[22];
  const float* bc   = (const float*)d_in[23];

  float* ws    = (float*)d_ws;
  float* hnode = ws + OFF_HN;
  float* XW    = ws + OFF_XW;
  float* H2    = ws + OFF_H2;
  float* asrc  = ws + OFF_ASRC;
  float* adst  = ws + OFF_ADST;
  float* emax  = ws + OFF_EMAX;
  float* den   = ws + OFF_DEN;
  float* sum1  = ws + OFF_STAT;
  float* sq1   = sum1 + 256;
  float* sum2  = sq1 + 256;
  float* sq2   = sum2 + 256;
  float* aff   = ws + OFF_AFF;
  float* A1 = aff, *B1s = aff+256, *A2 = aff+512, *B2s = aff+768, *WCP = aff+1024, *BIAS0 = aff+1280;
  int* cnt = (int*)(ws + OFF_INT);
  int* fil = cnt + NNODE;
  int* ptr = fil + NNODE;
  int* csr = ptr + NNODE + 1;

  const int* esrc = ei;
  const int* edst = ei + NEDGE;

  k_zero<<<dim3((2*NNODE+255)/256), dim3(256), 0, stream>>>((float*)cnt, 2*NNODE);
  k_zero<<<dim3(4), dim3(256), 0, stream>>>(sum1, 1024);
  k_count<<<dim3((NEDGE+255)/256), dim3(256), 0, stream>>>(edst, cnt);
  k_scan<<<dim3(1), dim3(1024), 0, stream>>>(cnt, ptr);
  k_fill<<<dim3((NEDGE+255)/256), dim3(256), 0, stream>>>(edst, ptr, fil, csr);

  k_lstm<<<dim3(MTOT/32), dim3(256), 0, stream>>>(x, Wih, Whh, bih, bhh, Wa, Wn, bnb, hnode);

  k_xw<64,false><<<dim3(MTOT/32), dim3(256), 0, stream>>>(hnode, W1, as1, ad1,
      (const float*)nullptr, (const float*)nullptr, XW, asrc, adst);
  k_stats<<<dim3(MTOT/4), dim3(256), 0, stream>>>(asrc, adst, esrc, csr, ptr, emax, den);
  k_agg<<<dim3(MTOT/4), dim3(256), 0, stream>>>(XW, asrc, adst, emax, den, esrc, csr, ptr, b1, H2);
  k_bnstats<<<dim3(256), dim3(256), 0, stream>>>(H2, sum1, sq1);
  k_bnfin<<<dim3(1), dim3(256), 0, stream>>>(sum1, sq1, g1, be1, A1, B1s);

  k_xw<256,true><<<dim3(MTOT/32), dim3(256), 0, stream>>>(H2, W2, as2, ad2, A1, B1s, XW, asrc, adst);
  k_stats<<<dim3(MTOT/4), dim3(256), 0, stream>>>(asrc, adst, esrc, csr, ptr, emax, den);
  k_agg<<<dim3(MTOT/4), dim3(256), 0, stream>>>(XW, asrc, adst, emax, den, esrc, csr, ptr, b2, H2);
  k_bnstats<<<dim3(256), dim3(256), 0, stream>>>(H2, sum2, sq2);
  k_bnfin<<<dim3(1), dim3(256), 0, stream>>>(sum2, sq2, g2, be2, A2, B2s);
  k_fold<<<dim3(1), dim3(256), 0, stream>>>(A2, B2s, Wcw, bc, WCP, BIAS0);

  k_out<<<dim3(MTOT/4), dim3(256), 0, stream>>>(H2, WCP, BIAS0, (float*)d_out);
}

// Round 8
// 1146.174 us; speedup vs baseline: 1.0930x; 1.0930x over previous
//
#include <hip/hip_runtime.h>

#define NBATCH 4
#define NNODE  10000
#define MTOT   40000
#define NEDGE  160000
#define NFEAT  57
#define RTDIM  78
#define XROW   291
#define SLOPE  0.2f
#define BNEPS  1e-5f

// ---- workspace layout (float element offsets) ----
#define OFF_HN   ((size_t)0)                         // MTOT*64
#define OFF_XW   ((size_t)MTOT*64)                   // MTOT*256
#define OFF_H2   (OFF_XW + (size_t)MTOT*256)         // MTOT*256
#define OFF_ASRC (OFF_H2 + (size_t)MTOT*256)         // MTOT*4
#define OFF_ADST (OFF_ASRC + (size_t)MTOT*4)
#define OFF_EMAX (OFF_ADST + (size_t)MTOT*4)
#define OFF_DEN  (OFF_EMAX + (size_t)MTOT*4)
#define OFF_STAT (OFF_DEN + (size_t)MTOT*4)          // 1024: sum1,sq1,sum2,sq2
#define OFF_AFF  (OFF_STAT + 1024)                   // a1,b1s,a2,b2s,wcp,bias0
#define OFF_INT  (OFF_AFF + 5*256 + 16)              // ints: cnt NN, fill NN, ptr NN+1, csr E

__device__ __forceinline__ float lrelu(float x){ return x > 0.f ? x : SLOPE*x; }
// fast sigmoid/tanh via v_exp_f32. tanh clamped so __expf never returns inf (no inf/inf NaN).
__device__ __forceinline__ float fsig(float x){ return __fdividef(1.f, 1.f + __expf(-x)); }
__device__ __forceinline__ float ftanh(float x){
  x = fminf(fmaxf(x, -15.f), 15.f);
  float t = __expf(2.f*x);
  return __fdividef(t - 1.f, t + 1.f);
}

// ------------------------- utility kernels -------------------------
__global__ __launch_bounds__(256) void k_zero(float* __restrict__ p, int n){
  int i = blockIdx.x*256 + threadIdx.x;
  if (i < n) p[i] = 0.f;
}

__global__ __launch_bounds__(256) void k_count(const int* __restrict__ dst, int* __restrict__ cnt){
  int e = blockIdx.x*256 + threadIdx.x;
  if (e < NEDGE) atomicAdd(&cnt[dst[e]], 1);
}

__global__ __launch_bounds__(1024) void k_scan(const int* __restrict__ cnt, int* __restrict__ ptr){
  __shared__ int sd[1024];
  int t = threadIdx.x;
  int loc[10]; int tot = 0;
  #pragma unroll
  for (int i=0;i<10;i++){
    int idx = t*10 + i;
    int v = (idx < NNODE) ? cnt[idx] : 0;
    loc[i] = tot; tot += v;
  }
  sd[t] = tot;
  __syncthreads();
  for (int off=1; off<1024; off<<=1){
    int v = (t >= off) ? sd[t-off] : 0;
    __syncthreads();
    sd[t] += v;
    __syncthreads();
  }
  int excl = sd[t] - tot;
  #pragma unroll
  for (int i=0;i<10;i++){
    int idx = t*10 + i;
    if (idx < NNODE) ptr[idx] = excl + loc[i];
  }
  if (t == 1023) ptr[NNODE] = sd[1023];
}

__global__ __launch_bounds__(256) void k_fill(const int* __restrict__ dst, const int* __restrict__ ptr,
                                              int* __restrict__ fil, int* __restrict__ csr){
  int e = blockIdx.x*256 + threadIdx.x;
  if (e >= NEDGE) return;
  int d = dst[e];
  int pos = ptr[d] + atomicAdd(&fil[d], 1);
  csr[pos] = e;
}

// ------------------------- fused LSTM + temporal attention + static branch -------------------------
// block: 256 threads = 4 waves, 32 nodes/block. lane j = hidden idx; wave grp owns 8 nodes.
// __launch_bounds__(256,3): VGPR cap ~170 -> 3 blocks/CU, no spill (256,4 spilled: 790MB scratch writes, R5).
__global__ __launch_bounds__(256, 3) void k_lstm(
    const float* __restrict__ x,
    const float* __restrict__ Wih, const float* __restrict__ Whh,
    const float* __restrict__ bih, const float* __restrict__ bhh,
    const float* __restrict__ Wa,
    const float* __restrict__ Wn, const float* __restrict__ bnb,
    float* __restrict__ hnode)
{
  __shared__ float Xs[32][80];
  __shared__ float Hs[32][64];
  __shared__ float WcL[256][20];
  const int tid = threadIdx.x;
  const int j   = tid & 63;
  const int grp = tid >> 6;
  const int mb  = blockIdx.x * 32;

  const float bg0 = bih[j]     + bhh[j];
  const float bg1 = bih[64+j]  + bhh[64+j];
  const float bg2 = bih[128+j] + bhh[128+j];
  const float bg3 = bih[192+j] + bhh[192+j];

  float c[8]; float ht0[8], ht1[8], ht2[8];
  #pragma unroll
  for (int i=0;i<8;i++) c[i] = 0.f;

  #pragma unroll
  for (int t=0; t<3; ++t) {
    __syncthreads();
    for (int idx = tid; idx < 32*80; idx += 256) {
      int node = idx / 80, k = idx - node*80;
      Xs[node][k] = (k < RTDIM) ? x[(size_t)(mb+node)*XROW + NFEAT + t*RTDIM + k] : 0.f;
    }
    float a0[8],a1[8],a2[8],a3[8];
    #pragma unroll
    for (int i=0;i<8;i++){a0[i]=0.f;a1[i]=0.f;a2[i]=0.f;a3[i]=0.f;}

    // ---- Wih phase: k = 0..79 (padded) ----
    for (int kc=0; kc<80; kc+=16) {
      __syncthreads();
      {
        int g0 = tid >> 2, q = tid & 3;
        #pragma unroll
        for (int gp=0; gp<4; ++gp) {
          int gate = g0 + gp*64;
          int k0 = kc + q*4;
          float4 v;
          v.x = (k0+0 < RTDIM) ? Wih[gate*RTDIM + k0+0] : 0.f;
          v.y = (k0+1 < RTDIM) ? Wih[gate*RTDIM + k0+1] : 0.f;
          v.z = (k0+2 < RTDIM) ? Wih[gate*RTDIM + k0+2] : 0.f;
          v.w = (k0+3 < RTDIM) ? Wih[gate*RTDIM + k0+3] : 0.f;
          *(float4*)&WcL[gate][q*4] = v;
        }
      }
      __syncthreads();
      #pragma unroll
      for (int k4=0;k4<4;++k4){
        const float4 w0 = *(const float4*)&WcL[j][k4*4];
        const float4 w1 = *(const float4*)&WcL[64+j][k4*4];
        const float4 w2 = *(const float4*)&WcL[128+j][k4*4];
        const float4 w3 = *(const float4*)&WcL[192+j][k4*4];
        #pragma unroll
        for (int i=0;i<8;++i){
          const float4 xv = *(const float4*)&Xs[grp*8+i][kc + k4*4];
          a0[i]=fmaf(w0.x,xv.x,a0[i]); a0[i]=fmaf(w0.y,xv.y,a0[i]); a0[i]=fmaf(w0.z,xv.z,a0[i]); a0[i]=fmaf(w0.w,xv.w,a0[i]);
          a1[i]=fmaf(w1.x,xv.x,a1[i]); a1[i]=fmaf(w1.y,xv.y,a1[i]); a1[i]=fmaf(w1.z,xv.z,a1[i]); a1[i]=fmaf(w1.w,xv.w,a1[i]);
          a2[i]=fmaf(w2.x,xv.x,a2[i]); a2[i]=fmaf(w2.y,xv.y,a2[i]); a2[i]=fmaf(w2.z,xv.z,a2[i]); a2[i]=fmaf(w2.w,xv.w,a2[i]);
          a3[i]=fmaf(w3.x,xv.x,a3[i]); a3[i]=fmaf(w3.y,xv.y,a3[i]); a3[i]=fmaf(w3.z,xv.z,a3[i]); a3[i]=fmaf(w3.w,xv.w,a3[i]);
        }
      }
    }
    // ---- Whh phase (skip at t=0, h0 == 0) ----
    if (t > 0) {
      for (int kc=0; kc<64; kc+=16) {
        __syncthreads();
        {
          int g0 = tid >> 2, q = tid & 3;
          #pragma unroll
          for (int gp=0; gp<4; ++gp) {
            int gate = g0 + gp*64;
            *(float4*)&WcL[gate][q*4] = *(const float4*)&Whh[gate*64 + kc + q*4];
          }
        }
        __syncthreads();
        #pragma unroll
        for (int k4=0;k4<4;++k4){
          const float4 w0 = *(const float4*)&WcL[j][k4*4];
          const float4 w1 = *(const float4*)&WcL[64+j][k4*4];
          const float4 w2 = *(const float4*)&WcL[128+j][k4*4];
          const float4 w3 = *(const float4*)&WcL[192+j][k4*4];
          #pragma unroll
          for (int i=0;i<8;++i){
            const float4 xv = *(const float4*)&Hs[grp*8+i][kc + k4*4];
            a0[i]=fmaf(w0.x,xv.x,a0[i]); a0[i]=fmaf(w0.y,xv.y,a0[i]); a0[i]=fmaf(w0.z,xv.z,a0[i]); a0[i]=fmaf(w0.w,xv.w,a0[i]);
            a1[i]=fmaf(w1.x,xv.x,a1[i]); a1[i]=fmaf(w1.y,xv.y,a1[i]); a1[i]=fmaf(w1.z,xv.z,a1[i]); a1[i]=fmaf(w1.w,xv.w,a1[i]);
            a2[i]=fmaf(w2.x,xv.x,a2[i]); a2[i]=fmaf(w2.y,xv.y,a2[i]); a2[i]=fmaf(w2.z,xv.z,a2[i]); a2[i]=fmaf(w2.w,xv.w,a2[i]);
            a3[i]=fmaf(w3.x,xv.x,a3[i]); a3[i]=fmaf(w3.y,xv.y,a3[i]); a3[i]=fmaf(w3.z,xv.z,a3[i]); a3[i]=fmaf(w3.w,xv.w,a3[i]);
          }
        }
      }
    }
    __syncthreads();  // all Hs reads done before overwrite
    #pragma unroll
    for (int i=0;i<8;++i){
      float iv = fsig(a0[i]+bg0);
      float fv = fsig(a1[i]+bg1);
      float gv = ftanh(a2[i]+bg2);
      float ov = fsig(a3[i]+bg3);
      float cc = fv*c[i] + iv*gv;
      c[i] = cc;
      float hv = ov * ftanh(cc);
      if (t == 0) ht0[i] = hv;
      else if (t == 1) ht1[i] = hv;
      else ht2[i] = hv;
      if (t < 2) Hs[grp*8+i][j] = hv;
    }
  }

  // ---- temporal attention (softmax over T; ba cancels) ----
  const float wa = Wa[j];
  float htemp[8];
  #pragma unroll
  for (int i=0;i<8;++i){
    float s0 = ht0[i]*wa, s1 = ht1[i]*wa, s2 = ht2[i]*wa;
    #pragma unroll
    for (int off=32; off; off>>=1){
      s0 += __shfl_xor(s0, off);
      s1 += __shfl_xor(s1, off);
      s2 += __shfl_xor(s2, off);
    }
    float mx = fmaxf(s0, fmaxf(s1, s2));
    float e0 = __expf(s0-mx), e1 = __expf(s1-mx), e2 = __expf(s2-mx);
    float inv = __fdividef(1.f, e0+e1+e2);
    htemp[i] = (e0*ht0[i] + e1*ht1[i] + e2*ht2[i]) * inv;
  }

  // ---- static branch: relu(node_f @ Wn^T + bnb) ----
  __syncthreads();
  for (int idx = tid; idx < 32*64; idx += 256){
    int node = idx >> 6, k = idx & 63;
    Xs[node][k] = (k < NFEAT) ? x[(size_t)(mb+node)*XROW + k] : 0.f;
  }
  float as_[8];
  #pragma unroll
  for (int i=0;i<8;++i) as_[i]=0.f;
  for (int kc=0; kc<64; kc+=16){
    __syncthreads();
    {
      int g0 = tid >> 2, q = tid & 3;   // 64 gates in one pass
      int k0 = kc + q*4;
      float4 v;
      v.x = (k0+0 < NFEAT) ? Wn[g0*NFEAT + k0+0] : 0.f;
      v.y = (k0+1 < NFEAT) ? Wn[g0*NFEAT + k0+1] : 0.f;
      v.z = (k0+2 < NFEAT) ? Wn[g0*NFEAT + k0+2] : 0.f;
      v.w = (k0+3 < NFEAT) ? Wn[g0*NFEAT + k0+3] : 0.f;
      *(float4*)&WcL[g0][q*4] = v;
    }
    __syncthreads();
    #pragma unroll
    for (int k4=0;k4<4;++k4){
      const float4 w = *(const float4*)&WcL[j][k4*4];
      #pragma unroll
      for (int i=0;i<8;++i){
        const float4 xv = *(const float4*)&Xs[grp*8+i][kc + k4*4];
        as_[i]=fmaf(w.x,xv.x,as_[i]); as_[i]=fmaf(w.y,xv.y,as_[i]);
        as_[i]=fmaf(w.z,xv.z,as_[i]); as_[i]=fmaf(w.w,xv.w,as_[i]);
      }
    }
  }
  const float bn = bnb[j];
  #pragma unroll
  for (int i=0;i<8;++i){
    float hs = as_[i] + bn; hs = hs > 0.f ? hs : 0.f;
    hnode[(size_t)(mb+grp*8+i)*64 + j] = htemp[i] + hs;
  }
}

// ------------------------- xw = in @ W^T (+BN affine on load) + fused asrc/adst -------------------------
template<int K, bool AFF>
__global__ __launch_bounds__(256, 3) void k_xw(
    const float* __restrict__ in, const float* __restrict__ W,
    const float* __restrict__ avs, const float* __restrict__ avd,
    const float* __restrict__ affA, const float* __restrict__ affB,
    float* __restrict__ XW, float* __restrict__ asrc, float* __restrict__ adst)
{
  __shared__ float Xs[32][K];
  __shared__ float WcL[256][20];
  const int tid = threadIdx.x;
  const int j   = tid & 63;
  const int grp = tid >> 6;
  const int mb  = blockIdx.x * 32;

  if constexpr (K == 256) {
    float sA = AFF ? affA[tid] : 1.f;
    float sB = AFF ? affB[tid] : 0.f;
    for (int node=0; node<32; ++node){
      float v = in[(size_t)(mb+node)*K + tid];
      Xs[node][tid] = v*sA + sB;
    }
  } else {
    for (int idx = tid; idx < 32*K; idx += 256){
      int node = idx / K, k = idx - node*K;
      Xs[node][k] = in[(size_t)(mb+node)*K + k];
    }
  }

  float a0[8],a1[8],a2[8],a3[8];
  #pragma unroll
  for (int i=0;i<8;i++){a0[i]=0.f;a1[i]=0.f;a2[i]=0.f;a3[i]=0.f;}

  for (int kc=0; kc<K; kc+=16){
    __syncthreads();
    {
      int g0 = tid >> 2, q = tid & 3;
      #pragma unroll
      for (int gp=0;gp<4;++gp){
        int gate = g0 + gp*64;
        *(float4*)&WcL[gate][q*4] = *(const float4*)&W[(size_t)gate*K + kc + q*4];
      }
    }
    __syncthreads();
    #pragma unroll
    for (int k4=0;k4<4;++k4){
      const float4 w0 = *(const float4*)&WcL[j][k4*4];
      const float4 w1 = *(const float4*)&WcL[64+j][k4*4];
      const float4 w2 = *(const float4*)&WcL[128+j][k4*4];
      const float4 w3 = *(const float4*)&WcL[192+j][k4*4];
      #pragma unroll
      for (int i=0;i<8;++i){
        const float4 xv = *(const float4*)&Xs[grp*8+i][kc + k4*4];
        a0[i]=fmaf(w0.x,xv.x,a0[i]); a0[i]=fmaf(w0.y,xv.y,a0[i]); a0[i]=fmaf(w0.z,xv.z,a0[i]); a0[i]=fmaf(w0.w,xv.w,a0[i]);
        a1[i]=fmaf(w1.x,xv.x,a1[i]); a1[i]=fmaf(w1.y,xv.y,a1[i]); a1[i]=fmaf(w1.z,xv.z,a1[i]); a1[i]=fmaf(w1.w,xv.w,a1[i]);
        a2[i]=fmaf(w2.x,xv.x,a2[i]); a2[i]=fmaf(w2.y,xv.y,a2[i]); a2[i]=fmaf(w2.z,xv.z,a2[i]); a2[i]=fmaf(w2.w,xv.w,a2[i]);
        a3[i]=fmaf(w3.x,xv.x,a3[i]); a3[i]=fmaf(w3.y,xv.y,a3[i]); a3[i]=fmaf(w3.z,xv.z,a3[i]); a3[i]=fmaf(w3.w,xv.w,a3[i]);
      }
    }
  }

  #pragma unroll
  for (int i=0;i<8;++i){
    size_t base = (size_t)(mb+grp*8+i)*256;
    XW[base + j]       = a0[i];
    XW[base + 64 + j]  = a1[i];
    XW[base + 128 + j] = a2[i];
    XW[base + 192 + j] = a3[i];
  }
  const float s0w = avs[j], s1w = avs[64+j], s2w = avs[128+j], s3w = avs[192+j];
  const float d0w = avd[j], d1w = avd[64+j], d2w = avd[128+j], d3w = avd[192+j];
  #pragma unroll
  for (int i=0;i<8;++i){
    float ps0=a0[i]*s0w, ps1=a1[i]*s1w, ps2=a2[i]*s2w, ps3=a3[i]*s3w;
    float pd0=a0[i]*d0w, pd1=a1[i]*d1w, pd2=a2[i]*d2w, pd3=a3[i]*d3w;
    #pragma unroll
    for (int off=32; off; off>>=1){
      ps0 += __shfl_xor(ps0, off); ps1 += __shfl_xor(ps1, off);
      ps2 += __shfl_xor(ps2, off); ps3 += __shfl_xor(ps3, off);
      pd0 += __shfl_xor(pd0, off); pd1 += __shfl_xor(pd1, off);
      pd2 += __shfl_xor(pd2, off); pd3 += __shfl_xor(pd3, off);
    }
    if (j == 0){
      int m = mb + grp*8 + i;
      asrc[m*4+0]=ps0; asrc[m*4+1]=ps1; asrc[m*4+2]=ps2; asrc[m*4+3]=ps3;
      adst[m*4+0]=pd0; adst[m*4+1]=pd1; adst[m*4+2]=pd2; adst[m*4+3]=pd3;
    }
  }
}

// ------------------------- per-dst softmax stats (max & denom incl. self loop) -------------------------
__global__ __launch_bounds__(256) void k_stats(
    const float* __restrict__ asrc, const float* __restrict__ adst,
    const int* __restrict__ esrc, const int* __restrict__ csr, const int* __restrict__ ptr,
    float* __restrict__ emax, float* __restrict__ den)
{
  const int m = blockIdx.x*4 + (threadIdx.x>>6);
  const int lane = threadIdx.x & 63;
  const int n = m % NNODE;
  const int bb = m / NNODE;
  const int s0 = ptr[n], s1 = ptr[n+1];
  const float4 ad  = *(const float4*)&adst[(size_t)m*4];
  const float4 asf = *(const float4*)&asrc[(size_t)m*4];
  const float ex0 = lrelu(asf.x+ad.x), ex1 = lrelu(asf.y+ad.y);
  const float ex2 = lrelu(asf.z+ad.z), ex3 = lrelu(asf.w+ad.w);
  float m0=ex0, m1=ex1, m2=ex2, m3=ex3;
  for (int e = s0+lane; e < s1; e += 64){
    int src = esrc[csr[e]];
    const float4 av = *(const float4*)&asrc[(size_t)(bb*NNODE+src)*4];
    m0 = fmaxf(m0, lrelu(av.x+ad.x));
    m1 = fmaxf(m1, lrelu(av.y+ad.y));
    m2 = fmaxf(m2, lrelu(av.z+ad.z));
    m3 = fmaxf(m3, lrelu(av.w+ad.w));
  }
  #pragma unroll
  for (int off=32; off; off>>=1){
    m0 = fmaxf(m0, __shfl_xor(m0, off));
    m1 = fmaxf(m1, __shfl_xor(m1, off));
    m2 = fmaxf(m2, __shfl_xor(m2, off));
    m3 = fmaxf(m3, __shfl_xor(m3, off));
  }
  float d0=0.f,d1=0.f,d2=0.f,d3=0.f;
  for (int e = s0+lane; e < s1; e += 64){
    int src = esrc[csr[e]];
    const float4 av = *(const float4*)&asrc[(size_t)(bb*NNODE+src)*4];
    d0 += __expf(lrelu(av.x+ad.x) - m0);
    d1 += __expf(lrelu(av.y+ad.y) - m1);
    d2 += __expf(lrelu(av.z+ad.z) - m2);
    d3 += __expf(lrelu(av.w+ad.w) - m3);
  }
  #pragma unroll
  for (int off=32; off; off>>=1){
    d0 += __shfl_xor(d0, off); d1 += __shfl_xor(d1, off);
    d2 += __shfl_xor(d2, off); d3 += __shfl_xor(d3, off);
  }
  d0 += __expf(ex0 - m0); d1 += __expf(ex1 - m1);
  d2 += __expf(ex2 - m2); d3 += __expf(ex3 - m3);
  if (lane == 0){
    float4 mv = {m0,m1,m2,m3}; *(float4*)&emax[(size_t)m*4] = mv;
    float4 dv = {d0,d1,d2,d3}; *(float4*)&den[(size_t)m*4]  = dv;
  }
}

// ------------------------- per-dst weighted aggregation + bias + relu -------------------------
__global__ __launch_bounds__(256) void k_agg(
    const float* __restrict__ XW, const float* __restrict__ asrc, const float* __restrict__ adst,
    const float* __restrict__ emax, const float* __restrict__ den,
    const int* __restrict__ esrc, const int* __restrict__ csr, const int* __restrict__ ptr,
    const float* __restrict__ bias, float* __restrict__ out)
{
  const int m = blockIdx.x*4 + (threadIdx.x>>6);
  const int lane = threadIdx.x & 63;
  const int h = lane >> 4;
  const int n = m % NNODE;
  const int bb = m / NNODE;
  const float adh  = adst[(size_t)m*4 + h];
  const float mxh  = emax[(size_t)m*4 + h];
  const float invd = __fdividef(1.f, den[(size_t)m*4 + h] + 1e-16f);
  float al = __expf(lrelu(asrc[(size_t)m*4+h] + adh) - mxh) * invd;
  float4 xv = *(const float4*)&XW[(size_t)m*256 + lane*4];
  float acx = al*xv.x, acy = al*xv.y, acz = al*xv.z, acw = al*xv.w;
  const int s0 = ptr[n], s1 = ptr[n+1];
  for (int e = s0; e < s1; ++e){
    int src = esrc[csr[e]];
    int ms = bb*NNODE + src;
    float a2 = __expf(lrelu(asrc[(size_t)ms*4+h] + adh) - mxh) * invd;
    float4 x2 = *(const float4*)&XW[(size_t)ms*256 + lane*4];
    acx = fmaf(a2, x2.x, acx); acy = fmaf(a2, x2.y, acy);
    acz = fmaf(a2, x2.z, acz); acw = fmaf(a2, x2.w, acw);
  }
  const float4 bv = *(const float4*)&bias[lane*4];
  acx = fmaxf(acx+bv.x, 0.f); acy = fmaxf(acy+bv.y, 0.f);
  acz = fmaxf(acz+bv.z, 0.f); acw = fmaxf(acw+bv.w, 0.f);
  float4 o = {acx,acy,acz,acw};
  *(float4*)&out[(size_t)m*256 + lane*4] = o;
}

// ------------------------- batchnorm -------------------------
__global__ __launch_bounds__(256) void k_bnstats(const float* __restrict__ H,
                                                 float* __restrict__ sum, float* __restrict__ sq){
  int c = threadIdx.x;
  float s = 0.f, q = 0.f;
  for (int r = blockIdx.x; r < MTOT; r += gridDim.x){
    float v = H[(size_t)r*256 + c];
    s += v; q += v*v;
  }
  atomicAdd(&sum[c], s);
  atomicAdd(&sq[c],  q);
}

__global__ __launch_bounds__(256) void k_bnfin(const float* __restrict__ sum, const float* __restrict__ sq,
    const float* __restrict__ g, const float* __restrict__ be,
    float* __restrict__ a, float* __restrict__ bsh)
{
  int c = threadIdx.x;
  float mean = sum[c] * (1.f/MTOT);
  float var  = sq[c]  * (1.f/MTOT) - mean*mean;
  float rstd = rsqrtf(var + BNEPS);
  float av = g[c] * rstd;
  a[c]   = av;
  bsh[c] = be[c] - mean*av;
}

__global__ __launch_bounds__(256) void k_fold(const float* __restrict__ a2, const float* __restrict__ b2s,
    const float* __restrict__ Wcw, const float* __restrict__ bc,
    float* __restrict__ wcp, float* __restrict__ bias0)
{
  __shared__ float red[256];
  int c = threadIdx.x;
  float w = Wcw[c];
  wcp[c] = a2[c]*w;
  red[c] = b2s[c]*w;
  __syncthreads();
  for (int off=128; off; off>>=1){
    if (c < off) red[c] += red[c+off];
    __syncthreads();
  }
  if (c == 0) bias0[0] = red[0] + bc[0];
}

// ------------------------- final projection -------------------------
__global__ __launch_bounds__(256) void k_out(const float* __restrict__ H, const float* __restrict__ wcp,
    const float* __restrict__ bias0, float* __restrict__ out)
{
  const int m = blockIdx.x*4 + (threadIdx.x>>6);
  const int lane = threadIdx.x & 63;
  const float4 h4 = *(const float4*)&H[(size_t)m*256 + lane*4];
  const float4 w4 = *(const float4*)&wcp[lane*4];
  float p = h4.x*w4.x + h4.y*w4.y + h4.z*w4.z + h4.w*w4.w;
  #pragma unroll
  for (int off=32; off; off>>=1) p += __shfl_xor(p, off);
  if (lane == 0) out[m] = p + bias0[0];
}

// ------------------------- launch -------------------------
extern "C" void kernel_launch(void* const* d_in, const int* in_sizes, int n_in,
                              void* d_out, int out_size, void* d_ws, size_t ws_size,
                              hipStream_t stream)
{
  const float* x    = (const float*)d_in[0];
  const int*   ei   = (const int*)d_in[1];
  const float* Wih  = (const float*)d_in[2];
  const float* Whh  = (const float*)d_in[3];
  const float* bih  = (const float*)d_in[4];
  const float* bhh  = (const float*)d_in[5];
  const float* Wa   = (const float*)d_in[6];
  const float* Wn   = (const float*)d_in[8];
  const float* bnb  = (const float*)d_in[9];
  const float* W1   = (const float*)d_in[10];
  const float* as1  = (const float*)d_in[11];
  const float* ad1  = (const float*)d_in[12];
  const float* b1   = (const float*)d_in[13];
  const float* W2   = (const float*)d_in[14];
  const float* as2  = (const float*)d_in[15];
  const float* ad2  = (const float*)d_in[16];
  const float* b2   = (const float*)d_in[17];
  const float* g1   = (const float*)d_in[18];
  const float* be1  = (const float*)d_in[19];
  const float* g2   = (const float*)d_in[20];
  const float* be2  = (const float*)d_in[21];
  const float* Wcw  = (const float*)d_in[22];
  const float* bc   = (const float*)d_in[23];

  float* ws    = (float*)d_ws;
  float* hnode = ws + OFF_HN;
  float* XW    = ws + OFF_XW;
  float* H2    = ws + OFF_H2;
  float* asrc  = ws + OFF_ASRC;
  float* adst  = ws + OFF_ADST;
  float* emax  = ws + OFF_EMAX;
  float* den   = ws + OFF_DEN;
  float* sum1  = ws + OFF_STAT;
  float* sq1   = sum1 + 256;
  float* sum2  = sq1 + 256;
  float* sq2   = sum2 + 256;
  float* aff   = ws + OFF_AFF;
  float* A1 = aff, *B1s = aff+256, *A2 = aff+512, *B2s = aff+768, *WCP = aff+1024, *BIAS0 = aff+1280;
  int* cnt = (int*)(ws + OFF_INT);
  int* fil = cnt + NNODE;
  int* ptr = fil + NNODE;
  int* csr = ptr + NNODE + 1;

  const int* esrc = ei;
  const int* edst = ei + NEDGE;

  k_zero<<<dim3((2*NNODE+255)/256), dim3(256), 0, stream>>>((float*)cnt, 2*NNODE);
  k_zero<<<dim3(4), dim3(256), 0, stream>>>(sum1, 1024);
  k_count<<<dim3((NEDGE+255)/256), dim3(256), 0, stream>>>(edst, cnt);
  k_scan<<<dim3(1), dim3(1024), 0, stream>>>(cnt, ptr);
  k_fill<<<dim3((NEDGE+255)/256), dim3(256), 0, stream>>>(edst, ptr, fil, csr);

  k_lstm<<<dim3(MTOT/32), dim3(256), 0, stream>>>(x, Wih, Whh, bih, bhh, Wa, Wn, bnb, hnode);

  k_xw<64,false><<<dim3(MTOT/32), dim3(256), 0, stream>>>(hnode, W1, as1, ad1,
      (const float*)nullptr, (const float*)nullptr, XW, asrc, adst);
  k_stats<<<dim3(MTOT/4), dim3(256), 0, stream>>>(asrc, adst, esrc, csr, ptr, emax, den);
  k_agg<<<dim3(MTOT/4), dim3(256), 0, stream>>>(XW, asrc, adst, emax, den, esrc, csr, ptr, b1, H2);
  k_bnstats<<<dim3(256), dim3(256), 0, stream>>>(H2, sum1, sq1);
  k_bnfin<<<dim3(1), dim3(256), 0, stream>>>(sum1, sq1, g1, be1, A1, B1s);

  k_xw<256,true><<<dim3(MTOT/32), dim3(256), 0, stream>>>(H2, W2, as2, ad2, A1, B1s, XW, asrc, adst);
  k_stats<<<dim3(MTOT/4), dim3(256), 0, stream>>>(asrc, adst, esrc, csr, ptr, emax, den);
  k_agg<<<dim3(MTOT/4), dim3(256), 0, stream>>>(XW, asrc, adst, emax, den, esrc, csr, ptr, b2, H2);
  k_bnstats<<<dim3(256), dim3(256), 0, stream>>>(H2, sum2, sq2);
  k_bnfin<<<dim3(1), dim3(256), 0, stream>>>(sum2, sq2, g2, be2, A2, B2s);
  k_fold<<<dim3(1), dim3(256), 0, stream>>>(A2, B2s, Wcw, bc, WCP, BIAS0);

  k_out<<<dim3(MTOT/4), dim3(256), 0, stream>>>(H2, WCP, BIAS0, (float*)d_out);
}

// Round 10
// 1101.042 us; speedup vs baseline: 1.1378x; 1.0410x over previous
//
#include <hip/hip_runtime.h>

#define NBATCH 4
#define NNODE  10000
#define MTOT   40000
#define NEDGE  160000
#define NFEAT  57
#define RTDIM  78
#define XROW   291
#define SLOPE  0.2f
#define BNEPS  1e-5f

// ---- workspace layout (float element offsets) ----
#define OFF_HN   ((size_t)0)                         // MTOT*64
#define OFF_XW   ((size_t)MTOT*64)                   // MTOT*256
#define OFF_H2   (OFF_XW + (size_t)MTOT*256)         // MTOT*256
#define OFF_ASRC (OFF_H2 + (size_t)MTOT*256)         // MTOT*4
#define OFF_ADST (OFF_ASRC + (size_t)MTOT*4)
#define OFF_EMAX (OFF_ADST + (size_t)MTOT*4)
#define OFF_DEN  (OFF_EMAX + (size_t)MTOT*4)
#define OFF_STAT (OFF_DEN + (size_t)MTOT*4)          // 1024: sum1,sq1,sum2,sq2
#define OFF_AFF  (OFF_STAT + 1024)                   // a1,b1s,a2,b2s,wcp,bias0
#define OFF_INT  (OFF_AFF + 5*256 + 16)              // ints: cnt NN, fill NN, ptr NN+1, csr E

__device__ __forceinline__ float lrelu(float x){ return x > 0.f ? x : SLOPE*x; }
// fast sigmoid/tanh via v_exp_f32. tanh clamped so __expf never returns inf (no inf/inf NaN).
__device__ __forceinline__ float fsig(float x){ return __fdividef(1.f, 1.f + __expf(-x)); }
__device__ __forceinline__ float ftanh(float x){
  x = fminf(fmaxf(x, -15.f), 15.f);
  float t = __expf(2.f*x);
  return __fdividef(t - 1.f, t + 1.f);
}

// ------------------------- utility kernels -------------------------
__global__ __launch_bounds__(256) void k_zero(float* __restrict__ p, int n){
  int i = blockIdx.x*256 + threadIdx.x;
  if (i < n) p[i] = 0.f;
}

__global__ __launch_bounds__(256) void k_count(const int* __restrict__ dst, int* __restrict__ cnt){
  int e = blockIdx.x*256 + threadIdx.x;
  if (e < NEDGE) atomicAdd(&cnt[dst[e]], 1);
}

__global__ __launch_bounds__(1024) void k_scan(const int* __restrict__ cnt, int* __restrict__ ptr){
  __shared__ int sd[1024];
  int t = threadIdx.x;
  int loc[10]; int tot = 0;
  #pragma unroll
  for (int i=0;i<10;i++){
    int idx = t*10 + i;
    int v = (idx < NNODE) ? cnt[idx] : 0;
    loc[i] = tot; tot += v;
  }
  sd[t] = tot;
  __syncthreads();
  for (int off=1; off<1024; off<<=1){
    int v = (t >= off) ? sd[t-off] : 0;
    __syncthreads();
    sd[t] += v;
    __syncthreads();
  }
  int excl = sd[t] - tot;
  #pragma unroll
  for (int i=0;i<10;i++){
    int idx = t*10 + i;
    if (idx < NNODE) ptr[idx] = excl + loc[i];
  }
  if (t == 1023) ptr[NNODE] = sd[1023];
}

__global__ __launch_bounds__(256) void k_fill(const int* __restrict__ dst, const int* __restrict__ ptr,
                                              int* __restrict__ fil, int* __restrict__ csr){
  int e = blockIdx.x*256 + threadIdx.x;
  if (e >= NEDGE) return;
  int d = dst[e];
  int pos = ptr[d] + atomicAdd(&fil[d], 1);
  csr[pos] = e;
}

// ------------------------- fused LSTM + temporal attention + static branch -------------------------
// block: 256 threads = 4 waves, 32 nodes/block. lane j = hidden idx; wave grp owns 8 nodes.
// __launch_bounds__ 2nd-arg calibration (this compiler, 256-thr blocks): cap ~= 256/arg.
//   (256,4)->64 VGPR (spill 790MB, R5); (256,3)->84 (spill 493MB, R8). Zero-spill extrap ~117.
//   (256,2)->cap 128: no spill predicted, 4 waves/SIMD.
__global__ __launch_bounds__(256, 2) void k_lstm(
    const float* __restrict__ x,
    const float* __restrict__ Wih, const float* __restrict__ Whh,
    const float* __restrict__ bih, const float* __restrict__ bhh,
    const float* __restrict__ Wa,
    const float* __restrict__ Wn, const float* __restrict__ bnb,
    float* __restrict__ hnode)
{
  __shared__ float Xs[32][80];
  __shared__ float Hs[32][64];
  __shared__ float WcL[256][20];
  const int tid = threadIdx.x;
  const int j   = tid & 63;
  const int grp = tid >> 6;
  const int mb  = blockIdx.x * 32;

  const float bg0 = bih[j]     + bhh[j];
  const float bg1 = bih[64+j]  + bhh[64+j];
  const float bg2 = bih[128+j] + bhh[128+j];
  const float bg3 = bih[192+j] + bhh[192+j];

  float c[8]; float ht0[8], ht1[8], ht2[8];
  #pragma unroll
  for (int i=0;i<8;i++) c[i] = 0.f;

  #pragma unroll
  for (int t=0; t<3; ++t) {
    __syncthreads();
    for (int idx = tid; idx < 32*80; idx += 256) {
      int node = idx / 80, k = idx - node*80;
      Xs[node][k] = (k < RTDIM) ? x[(size_t)(mb+node)*XROW + NFEAT + t*RTDIM + k] : 0.f;
    }
    float a0[8],a1[8],a2[8],a3[8];
    #pragma unroll
    for (int i=0;i<8;i++){a0[i]=0.f;a1[i]=0.f;a2[i]=0.f;a3[i]=0.f;}

    // ---- Wih phase: k = 0..79 (padded) ----
    for (int kc=0; kc<80; kc+=16) {
      __syncthreads();
      {
        int g0 = tid >> 2, q = tid & 3;
        #pragma unroll
        for (int gp=0; gp<4; ++gp) {
          int gate = g0 + gp*64;
          int k0 = kc + q*4;
          float4 v;
          v.x = (k0+0 < RTDIM) ? Wih[gate*RTDIM + k0+0] : 0.f;
          v.y = (k0+1 < RTDIM) ? Wih[gate*RTDIM + k0+1] : 0.f;
          v.z = (k0+2 < RTDIM) ? Wih[gate*RTDIM + k0+2] : 0.f;
          v.w = (k0+3 < RTDIM) ? Wih[gate*RTDIM + k0+3] : 0.f;
          *(float4*)&WcL[gate][q*4] = v;
        }
      }
      __syncthreads();
      #pragma unroll
      for (int k4=0;k4<4;++k4){
        const float4 w0 = *(const float4*)&WcL[j][k4*4];
        const float4 w1 = *(const float4*)&WcL[64+j][k4*4];
        const float4 w2 = *(const float4*)&WcL[128+j][k4*4];
        const float4 w3 = *(const float4*)&WcL[192+j][k4*4];
        #pragma unroll
        for (int i=0;i<8;++i){
          const float4 xv = *(const float4*)&Xs[grp*8+i][kc + k4*4];
          a0[i]=fmaf(w0.x,xv.x,a0[i]); a0[i]=fmaf(w0.y,xv.y,a0[i]); a0[i]=fmaf(w0.z,xv.z,a0[i]); a0[i]=fmaf(w0.w,xv.w,a0[i]);
          a1[i]=fmaf(w1.x,xv.x,a1[i]); a1[i]=fmaf(w1.y,xv.y,a1[i]); a1[i]=fmaf(w1.z,xv.z,a1[i]); a1[i]=fmaf(w1.w,xv.w,a1[i]);
          a2[i]=fmaf(w2.x,xv.x,a2[i]); a2[i]=fmaf(w2.y,xv.y,a2[i]); a2[i]=fmaf(w2.z,xv.z,a2[i]); a2[i]=fmaf(w2.w,xv.w,a2[i]);
          a3[i]=fmaf(w3.x,xv.x,a3[i]); a3[i]=fmaf(w3.y,xv.y,a3[i]); a3[i]=fmaf(w3.z,xv.z,a3[i]); a3[i]=fmaf(w3.w,xv.w,a3[i]);
        }
      }
    }
    // ---- Whh phase (skip at t=0, h0 == 0) ----
    if (t > 0) {
      for (int kc=0; kc<64; kc+=16) {
        __syncthreads();
        {
          int g0 = tid >> 2, q = tid & 3;
          #pragma unroll
          for (int gp=0; gp<4; ++gp) {
            int gate = g0 + gp*64;
            *(float4*)&WcL[gate][q*4] = *(const float4*)&Whh[gate*64 + kc + q*4];
          }
        }
        __syncthreads();
        #pragma unroll
        for (int k4=0;k4<4;++k4){
          const float4 w0 = *(const float4*)&WcL[j][k4*4];
          const float4 w1 = *(const float4*)&WcL[64+j][k4*4];
          const float4 w2 = *(const float4*)&WcL[128+j][k4*4];
          const float4 w3 = *(const float4*)&WcL[192+j][k4*4];
          #pragma unroll
          for (int i=0;i<8;++i){
            const float4 xv = *(const float4*)&Hs[grp*8+i][kc + k4*4];
            a0[i]=fmaf(w0.x,xv.x,a0[i]); a0[i]=fmaf(w0.y,xv.y,a0[i]); a0[i]=fmaf(w0.z,xv.z,a0[i]); a0[i]=fmaf(w0.w,xv.w,a0[i]);
            a1[i]=fmaf(w1.x,xv.x,a1[i]); a1[i]=fmaf(w1.y,xv.y,a1[i]); a1[i]=fmaf(w1.z,xv.z,a1[i]); a1[i]=fmaf(w1.w,xv.w,a1[i]);
            a2[i]=fmaf(w2.x,xv.x,a2[i]); a2[i]=fmaf(w2.y,xv.y,a2[i]); a2[i]=fmaf(w2.z,xv.z,a2[i]); a2[i]=fmaf(w2.w,xv.w,a2[i]);
            a3[i]=fmaf(w3.x,xv.x,a3[i]); a3[i]=fmaf(w3.y,xv.y,a3[i]); a3[i]=fmaf(w3.z,xv.z,a3[i]); a3[i]=fmaf(w3.w,xv.w,a3[i]);
          }
        }
      }
    }
    __syncthreads();  // all Hs reads done before overwrite
    #pragma unroll
    for (int i=0;i<8;++i){
      float iv = fsig(a0[i]+bg0);
      float fv = fsig(a1[i]+bg1);
      float gv = ftanh(a2[i]+bg2);
      float ov = fsig(a3[i]+bg3);
      float cc = fv*c[i] + iv*gv;
      c[i] = cc;
      float hv = ov * ftanh(cc);
      if (t == 0) ht0[i] = hv;
      else if (t == 1) ht1[i] = hv;
      else ht2[i] = hv;
      if (t < 2) Hs[grp*8+i][j] = hv;
    }
  }

  // ---- temporal attention (softmax over T; ba cancels) ----
  const float wa = Wa[j];
  float htemp[8];
  #pragma unroll
  for (int i=0;i<8;++i){
    float s0 = ht0[i]*wa, s1 = ht1[i]*wa, s2 = ht2[i]*wa;
    #pragma unroll
    for (int off=32; off; off>>=1){
      s0 += __shfl_xor(s0, off);
      s1 += __shfl_xor(s1, off);
      s2 += __shfl_xor(s2, off);
    }
    float mx = fmaxf(s0, fmaxf(s1, s2));
    float e0 = __expf(s0-mx), e1 = __expf(s1-mx), e2 = __expf(s2-mx);
    float inv = __fdividef(1.f, e0+e1+e2);
    htemp[i] = (e0*ht0[i] + e1*ht1[i] + e2*ht2[i]) * inv;
  }

  // ---- static branch: relu(node_f @ Wn^T + bnb) ----
  __syncthreads();
  for (int idx = tid; idx < 32*64; idx += 256){
    int node = idx >> 6, k = idx & 63;
    Xs[node][k] = (k < NFEAT) ? x[(size_t)(mb+node)*XROW + k] : 0.f;
  }
  float as_[8];
  #pragma unroll
  for (int i=0;i<8;++i) as_[i]=0.f;
  for (int kc=0; kc<64; kc+=16){
    __syncthreads();
    {
      int g0 = tid >> 2, q = tid & 3;   // 64 gates in one pass
      int k0 = kc + q*4;
      float4 v;
      v.x = (k0+0 < NFEAT) ? Wn[g0*NFEAT + k0+0] : 0.f;
      v.y = (k0+1 < NFEAT) ? Wn[g0*NFEAT + k0+1] : 0.f;
      v.z = (k0+2 < NFEAT) ? Wn[g0*NFEAT + k0+2] : 0.f;
      v.w = (k0+3 < NFEAT) ? Wn[g0*NFEAT + k0+3] : 0.f;
      *(float4*)&WcL[g0][q*4] = v;
    }
    __syncthreads();
    #pragma unroll
    for (int k4=0;k4<4;++k4){
      const float4 w = *(const float4*)&WcL[j][k4*4];
      #pragma unroll
      for (int i=0;i<8;++i){
        const float4 xv = *(const float4*)&Xs[grp*8+i][kc + k4*4];
        as_[i]=fmaf(w.x,xv.x,as_[i]); as_[i]=fmaf(w.y,xv.y,as_[i]);
        as_[i]=fmaf(w.z,xv.z,as_[i]); as_[i]=fmaf(w.w,xv.w,as_[i]);
      }
    }
  }
  const float bn = bnb[j];
  #pragma unroll
  for (int i=0;i<8;++i){
    float hs = as_[i] + bn; hs = hs > 0.f ? hs : 0.f;
    hnode[(size_t)(mb+grp*8+i)*64 + j] = htemp[i] + hs;
  }
}

// ------------------------- xw = in @ W^T (+BN affine on load) + fused asrc/adst -------------------------
template<int K, bool AFF>
__global__ __launch_bounds__(256, 2) void k_xw(
    const float* __restrict__ in, const float* __restrict__ W,
    const float* __restrict__ avs, const float* __restrict__ avd,
    const float* __restrict__ affA, const float* __restrict__ affB,
    float* __restrict__ XW, float* __restrict__ asrc, float* __restrict__ adst)
{
  __shared__ float Xs[32][K];
  __shared__ float WcL[256][20];
  const int tid = threadIdx.x;
  const int j   = tid & 63;
  const int grp = tid >> 6;
  const int mb  = blockIdx.x * 32;

  if constexpr (K == 256) {
    float sA = AFF ? affA[tid] : 1.f;
    float sB = AFF ? affB[tid] : 0.f;
    for (int node=0; node<32; ++node){
      float v = in[(size_t)(mb+node)*K + tid];
      Xs[node][tid] = v*sA + sB;
    }
  } else {
    for (int idx = tid; idx < 32*K; idx += 256){
      int node = idx / K, k = idx - node*K;
      Xs[node][k] = in[(size_t)(mb+node)*K + k];
    }
  }

  float a0[8],a1[8],a2[8],a3[8];
  #pragma unroll
  for (int i=0;i<8;i++){a0[i]=0.f;a1[i]=0.f;a2[i]=0.f;a3[i]=0.f;}

  for (int kc=0; kc<K; kc+=16){
    __syncthreads();
    {
      int g0 = tid >> 2, q = tid & 3;
      #pragma unroll
      for (int gp=0;gp<4;++gp){
        int gate = g0 + gp*64;
        *(float4*)&WcL[gate][q*4] = *(const float4*)&W[(size_t)gate*K + kc + q*4];
      }
    }
    __syncthreads();
    #pragma unroll
    for (int k4=0;k4<4;++k4){
      const float4 w0 = *(const float4*)&WcL[j][k4*4];
      const float4 w1 = *(const float4*)&WcL[64+j][k4*4];
      const float4 w2 = *(const float4*)&WcL[128+j][k4*4];
      const float4 w3 = *(const float4*)&WcL[192+j][k4*4];
      #pragma unroll
      for (int i=0;i<8;++i){
        const float4 xv = *(const float4*)&Xs[grp*8+i][kc + k4*4];
        a0[i]=fmaf(w0.x,xv.x,a0[i]); a0[i]=fmaf(w0.y,xv.y,a0[i]); a0[i]=fmaf(w0.z,xv.z,a0[i]); a0[i]=fmaf(w0.w,xv.w,a0[i]);
        a1[i]=fmaf(w1.x,xv.x,a1[i]); a1[i]=fmaf(w1.y,xv.y,a1[i]); a1[i]=fmaf(w1.z,xv.z,a1[i]); a1[i]=fmaf(w1.w,xv.w,a1[i]);
        a2[i]=fmaf(w2.x,xv.x,a2[i]); a2[i]=fmaf(w2.y,xv.y,a2[i]); a2[i]=fmaf(w2.z,xv.z,a2[i]); a2[i]=fmaf(w2.w,xv.w,a2[i]);
        a3[i]=fmaf(w3.x,xv.x,a3[i]); a3[i]=fmaf(w3.y,xv.y,a3[i]); a3[i]=fmaf(w3.z,xv.z,a3[i]); a3[i]=fmaf(w3.w,xv.w,a3[i]);
      }
    }
  }

  #pragma unroll
  for (int i=0;i<8;++i){
    size_t base = (size_t)(mb+grp*8+i)*256;
    XW[base + j]       = a0[i];
    XW[base + 64 + j]  = a1[i];
    XW[base + 128 + j] = a2[i];
    XW[base + 192 + j] = a3[i];
  }
  const float s0w = avs[j], s1w = avs[64+j], s2w = avs[128+j], s3w = avs[192+j];
  const float d0w = avd[j], d1w = avd[64+j], d2w = avd[128+j], d3w = avd[192+j];
  #pragma unroll
  for (int i=0;i<8;++i){
    float ps0=a0[i]*s0w, ps1=a1[i]*s1w, ps2=a2[i]*s2w, ps3=a3[i]*s3w;
    float pd0=a0[i]*d0w, pd1=a1[i]*d1w, pd2=a2[i]*d2w, pd3=a3[i]*d3w;
    #pragma unroll
    for (int off=32; off; off>>=1){
      ps0 += __shfl_xor(ps0, off); ps1 += __shfl_xor(ps1, off);
      ps2 += __shfl_xor(ps2, off); ps3 += __shfl_xor(ps3, off);
      pd0 += __shfl_xor(pd0, off); pd1 += __shfl_xor(pd1, off);
      pd2 += __shfl_xor(pd2, off); pd3 += __shfl_xor(pd3, off);
    }
    if (j == 0){
      int m = mb + grp*8 + i;
      asrc[m*4+0]=ps0; asrc[m*4+1]=ps1; asrc[m*4+2]=ps2; asrc[m*4+3]=ps3;
      adst[m*4+0]=pd0; adst[m*4+1]=pd1; adst[m*4+2]=pd2; adst[m*4+3]=pd3;
    }
  }
}

// ------------------------- per-dst softmax stats (max & denom incl. self loop) -------------------------
__global__ __launch_bounds__(256) void k_stats(
    const float* __restrict__ asrc, const float* __restrict__ adst,
    const int* __restrict__ esrc, const int* __restrict__ csr, const int* __restrict__ ptr,
    float* __restrict__ emax, float* __restrict__ den)
{
  const int m = blockIdx.x*4 + (threadIdx.x>>6);
  const int lane = threadIdx.x & 63;
  const int n = m % NNODE;
  const int bb = m / NNODE;
  const int s0 = ptr[n], s1 = ptr[n+1];
  const float4 ad  = *(const float4*)&adst[(size_t)m*4];
  const float4 asf = *(const float4*)&asrc[(size_t)m*4];
  const float ex0 = lrelu(asf.x+ad.x), ex1 = lrelu(asf.y+ad.y);
  const float ex2 = lrelu(asf.z+ad.z), ex3 = lrelu(asf.w+ad.w);
  float m0=ex0, m1=ex1, m2=ex2, m3=ex3;
  for (int e = s0+lane; e < s1; e += 64){
    int src = esrc[csr[e]];
    const float4 av = *(const float4*)&asrc[(size_t)(bb*NNODE+src)*4];
    m0 = fmaxf(m0, lrelu(av.x+ad.x));
    m1 = fmaxf(m1, lrelu(av.y+ad.y));
    m2 = fmaxf(m2, lrelu(av.z+ad.z));
    m3 = fmaxf(m3, lrelu(av.w+ad.w));
  }
  #pragma unroll
  for (int off=32; off; off>>=1){
    m0 = fmaxf(m0, __shfl_xor(m0, off));
    m1 = fmaxf(m1, __shfl_xor(m1, off));
    m2 = fmaxf(m2, __shfl_xor(m2, off));
    m3 = fmaxf(m3, __shfl_xor(m3, off));
  }
  float d0=0.f,d1=0.f,d2=0.f,d3=0.f;
  for (int e = s0+lane; e < s1; e += 64){
    int src = esrc[csr[e]];
    const float4 av = *(const float4*)&asrc[(size_t)(bb*NNODE+src)*4];
    d0 += __expf(lrelu(av.x+ad.x) - m0);
    d1 += __expf(lrelu(av.y+ad.y) - m1);
    d2 += __expf(lrelu(av.z+ad.z) - m2);
    d3 += __expf(lrelu(av.w+ad.w) - m3);
  }
  #pragma unroll
  for (int off=32; off; off>>=1){
    d0 += __shfl_xor(d0, off); d1 += __shfl_xor(d1, off);
    d2 += __shfl_xor(d2, off); d3 += __shfl_xor(d3, off);
  }
  d0 += __expf(ex0 - m0); d1 += __expf(ex1 - m1);
  d2 += __expf(ex2 - m2); d3 += __expf(ex3 - m3);
  if (lane == 0){
    float4 mv = {m0,m1,m2,m3}; *(float4*)&emax[(size_t)m*4] = mv;
    float4 dv = {d0,d1,d2,d3}; *(float4*)&den[(size_t)m*4]  = dv;
  }
}

// ------------------------- per-dst weighted aggregation + bias + relu -------------------------
__global__ __launch_bounds__(256) void k_agg(
    const float* __restrict__ XW, const float* __restrict__ asrc, const float* __restrict__ adst,
    const float* __restrict__ emax, const float* __restrict__ den,
    const int* __restrict__ esrc, const int* __restrict__ csr, const int* __restrict__ ptr,
    const float* __restrict__ bias, float* __restrict__ out)
{
  const int m = blockIdx.x*4 + (threadIdx.x>>6);
  const int lane = threadIdx.x & 63;
  const int h = lane >> 4;
  const int n = m % NNODE;
  const int bb = m / NNODE;
  const float adh  = adst[(size_t)m*4 + h];
  const float mxh  = emax[(size_t)m*4 + h];
  const float invd = __fdividef(1.f, den[(size_t)m*4 + h] + 1e-16f);
  float al = __expf(lrelu(asrc[(size_t)m*4+h] + adh) - mxh) * invd;
  float4 xv = *(const float4*)&XW[(size_t)m*256 + lane*4];
  float acx = al*xv.x, acy = al*xv.y, acz = al*xv.z, acw = al*xv.w;
  const int s0 = ptr[n], s1 = ptr[n+1];
  for (int e = s0; e < s1; ++e){
    int src = esrc[csr[e]];
    int ms = bb*NNODE + src;
    float a2 = __expf(lrelu(asrc[(size_t)ms*4+h] + adh) - mxh) * invd;
    float4 x2 = *(const float4*)&XW[(size_t)ms*256 + lane*4];
    acx = fmaf(a2, x2.x, acx); acy = fmaf(a2, x2.y, acy);
    acz = fmaf(a2, x2.z, acz); acw = fmaf(a2, x2.w, acw);
  }
  const float4 bv = *(const float4*)&bias[lane*4];
  acx = fmaxf(acx+bv.x, 0.f); acy = fmaxf(acy+bv.y, 0.f);
  acz = fmaxf(acz+bv.z, 0.f); acw = fmaxf(acw+bv.w, 0.f);
  float4 o = {acx,acy,acz,acw};
  *(float4*)&out[(size_t)m*256 + lane*4] = o;
}

// ------------------------- batchnorm -------------------------
__global__ __launch_bounds__(256) void k_bnstats(const float* __restrict__ H,
                                                 float* __restrict__ sum, float* __restrict__ sq){
  int c = threadIdx.x;
  float s = 0.f, q = 0.f;
  for (int r = blockIdx.x; r < MTOT; r += gridDim.x){
    float v = H[(size_t)r*256 + c];
    s += v; q += v*v;
  }
  atomicAdd(&sum[c], s);
  atomicAdd(&sq[c],  q);
}

__global__ __launch_bounds__(256) void k_bnfin(const float* __restrict__ sum, const float* __restrict__ sq,
    const float* __restrict__ g, const float* __restrict__ be,
    float* __restrict__ a, float* __restrict__ bsh)
{
  int c = threadIdx.x;
  float mean = sum[c] * (1.f/MTOT);
  float var  = sq[c]  * (1.f/MTOT) - mean*mean;
  float rstd = rsqrtf(var + BNEPS);
  float av = g[c] * rstd;
  a[c]   = av;
  bsh[c] = be[c] - mean*av;
}

__global__ __launch_bounds__(256) void k_fold(const float* __restrict__ a2, const float* __restrict__ b2s,
    const float* __restrict__ Wcw, const float* __restrict__ bc,
    float* __restrict__ wcp, float* __restrict__ bias0)
{
  __shared__ float red[256];
  int c = threadIdx.x;
  float w = Wcw[c];
  wcp[c] = a2[c]*w;
  red[c] = b2s[c]*w;
  __syncthreads();
  for (int off=128; off; off>>=1){
    if (c < off) red[c] += red[c+off];
    __syncthreads();
  }
  if (c == 0) bias0[0] = red[0] + bc[0];
}

// ------------------------- final projection -------------------------
__global__ __launch_bounds__(256) void k_out(const float* __restrict__ H, const float* __restrict__ wcp,
    const float* __restrict__ bias0, float* __restrict__ out)
{
  const int m = blockIdx.x*4 + (threadIdx.x>>6);
  const int lane = threadIdx.x & 63;
  const float4 h4 = *(const float4*)&H[(size_t)m*256 + lane*4];
  const float4 w4 = *(const float4*)&wcp[lane*4];
  float p = h4.x*w4.x + h4.y*w4.y + h4.z*w4.z + h4.w*w4.w;
  #pragma unroll
  for (int off=32; off; off>>=1) p += __shfl_xor(p, off);
  if (lane == 0) out[m] = p + bias0[0];
}

// ------------------------- launch -------------------------
extern "C" void kernel_launch(void* const* d_in, const int* in_sizes, int n_in,
                              void* d_out, int out_size, void* d_ws, size_t ws_size,
                              hipStream_t stream)
{
  const float* x    = (const float*)d_in[0];
  const int*   ei   = (const int*)d_in[1];
  const float* Wih  = (const float*)d_in[2];
  const float* Whh  = (const float*)d_in[3];
  const float* bih  = (const float*)d_in[4];
  const float* bhh  = (const float*)d_in[5];
  const float* Wa   = (const float*)d_in[6];
  const float* Wn   = (const float*)d_in[8];
  const float* bnb  = (const float*)d_in[9];
  const float* W1   = (const float*)d_in[10];
  const float* as1  = (const float*)d_in[11];
  const float* ad1  = (const float*)d_in[12];
  const float* b1   = (const float*)d_in[13];
  const float* W2   = (const float*)d_in[14];
  const float* as2  = (const float*)d_in[15];
  const float* ad2  = (const float*)d_in[16];
  const float* b2   = (const float*)d_in[17];
  const float* g1   = (const float*)d_in[18];
  const float* be1  = (const float*)d_in[19];
  const float* g2   = (const float*)d_in[20];
  const float* be2  = (const float*)d_in[21];
  const float* Wcw  = (const float*)d_in[22];
  const float* bc   = (const float*)d_in[23];

  float* ws    = (float*)d_ws;
  float* hnode = ws + OFF_HN;
  float* XW    = ws + OFF_XW;
  float* H2    = ws + OFF_H2;
  float* asrc  = ws + OFF_ASRC;
  float* adst  = ws + OFF_ADST;
  float* emax  = ws + OFF_EMAX;
  float* den   = ws + OFF_DEN;
  float* sum1  = ws + OFF_STAT;
  float* sq1   = sum1 + 256;
  float* sum2  = sq1 + 256;
  float* sq2   = sum2 + 256;
  float* aff   = ws + OFF_AFF;
  float* A1 = aff, *B1s = aff+256, *A2 = aff+512, *B2s = aff+768, *WCP = aff+1024, *BIAS0 = aff+1280;
  int* cnt = (int*)(ws + OFF_INT);
  int* fil = cnt + NNODE;
  int* ptr = fil + NNODE;
  int* csr = ptr + NNODE + 1;

  const int* esrc = ei;
  const int* edst = ei + NEDGE;

  k_zero<<<dim3((2*NNODE+255)/256), dim3(256), 0, stream>>>((float*)cnt, 2*NNODE);
  k_zero<<<dim3(4), dim3(256), 0, stream>>>(sum1, 1024);
  k_count<<<dim3((NEDGE+255)/256), dim3(256), 0, stream>>>(edst, cnt);
  k_scan<<<dim3(1), dim3(1024), 0, stream>>>(cnt, ptr);
  k_fill<<<dim3((NEDGE+255)/256), dim3(256), 0, stream>>>(edst, ptr, fil, csr);

  k_lstm<<<dim3(MTOT/32), dim3(256), 0, stream>>>(x, Wih, Whh, bih, bhh, Wa, Wn, bnb, hnode);

  k_xw<64,false><<<dim3(MTOT/32), dim3(256), 0, stream>>>(hnode, W1, as1, ad1,
      (const float*)nullptr, (const float*)nullptr, XW, asrc, adst);
  k_stats<<<dim3(MTOT/4), dim3(256), 0, stream>>>(asrc, adst, esrc, csr, ptr, emax, den);
  k_agg<<<dim3(MTOT/4), dim3(256), 0, stream>>>(XW, asrc, adst, emax, den, esrc, csr, ptr, b1, H2);
  k_bnstats<<<dim3(256), dim3(256), 0, stream>>>(H2, sum1, sq1);
  k_bnfin<<<dim3(1), dim3(256), 0, stream>>>(sum1, sq1, g1, be1, A1, B1s);

  k_xw<256,true><<<dim3(MTOT/32), dim3(256), 0, stream>>>(H2, W2, as2, ad2, A1, B1s, XW, asrc, adst);
  k_stats<<<dim3(MTOT/4), dim3(256), 0, stream>>>(asrc, adst, esrc, csr, ptr, emax, den);
  k_agg<<<dim3(MTOT/4), dim3(256), 0, stream>>>(XW, asrc, adst, emax, den, esrc, csr, ptr, b2, H2);
  k_bnstats<<<dim3(256), dim3(256), 0, stream>>>(H2, sum2, sq2);
  k_bnfin<<<dim3(1), dim3(256), 0, stream>>>(sum2, sq2, g2, be2, A2, B2s);
  k_fold<<<dim3(1), dim3(256), 0, stream>>>(A2, B2s, Wcw, bc, WCP, BIAS0);

  k_out<<<dim3(MTOT/4), dim3(256), 0, stream>>>(H2, WCP, BIAS0, (float*)d_out);
}

// Round 12
// 982.924 us; speedup vs baseline: 1.2745x; 1.1202x over previous
//
#include <hip/hip_runtime.h>

#define NBATCH 4
#define NNODE  10000
#define MTOT   40000
#define NEDGE  160000
#define NFEAT  57
#define RTDIM  78
#define XROW   291
#define SLOPE  0.2f
#define BNEPS  1e-5f

// ---- workspace layout (float element offsets) ----
#define OFF_HN   ((size_t)0)                         // MTOT*64
#define OFF_XW   ((size_t)MTOT*64)                   // MTOT*256
#define OFF_H2   (OFF_XW + (size_t)MTOT*256)         // MTOT*256
#define OFF_ASRC (OFF_H2 + (size_t)MTOT*256)         // MTOT*4
#define OFF_ADST (OFF_ASRC + (size_t)MTOT*4)
#define OFF_EMAX (OFF_ADST + (size_t)MTOT*4)
#define OFF_DEN  (OFF_EMAX + (size_t)MTOT*4)
#define OFF_STAT (OFF_DEN + (size_t)MTOT*4)          // 1024: sum1,sq1,sum2,sq2
#define OFF_AFF  (OFF_STAT + 1024)                   // a1,b1s,a2,b2s,wcp,bias0
#define OFF_INT  (OFF_AFF + 5*256 + 16)              // ints: cnt NN, fill NN, ptr NN+1, csr E

__device__ __forceinline__ float lrelu(float x){ return x > 0.f ? x : SLOPE*x; }
// fast sigmoid/tanh via v_exp_f32. tanh clamped so __expf never returns inf (no inf/inf NaN).
__device__ __forceinline__ float fsig(float x){ return __fdividef(1.f, 1.f + __expf(-x)); }
__device__ __forceinline__ float ftanh(float x){
  x = fminf(fmaxf(x, -15.f), 15.f);
  float t = __expf(2.f*x);
  return __fdividef(t - 1.f, t + 1.f);
}

// ------------------------- utility kernels -------------------------
__global__ __launch_bounds__(256) void k_zero(float* __restrict__ p, int n){
  int i = blockIdx.x*256 + threadIdx.x;
  if (i < n) p[i] = 0.f;
}

__global__ __launch_bounds__(256) void k_count(const int* __restrict__ dst, int* __restrict__ cnt){
  int e = blockIdx.x*256 + threadIdx.x;
  if (e < NEDGE) atomicAdd(&cnt[dst[e]], 1);
}

__global__ __launch_bounds__(1024) void k_scan(const int* __restrict__ cnt, int* __restrict__ ptr){
  __shared__ int sd[1024];
  int t = threadIdx.x;
  int loc[10]; int tot = 0;
  #pragma unroll
  for (int i=0;i<10;i++){
    int idx = t*10 + i;
    int v = (idx < NNODE) ? cnt[idx] : 0;
    loc[i] = tot; tot += v;
  }
  sd[t] = tot;
  __syncthreads();
  for (int off=1; off<1024; off<<=1){
    int v = (t >= off) ? sd[t-off] : 0;
    __syncthreads();
    sd[t] += v;
    __syncthreads();
  }
  int excl = sd[t] - tot;
  #pragma unroll
  for (int i=0;i<10;i++){
    int idx = t*10 + i;
    if (idx < NNODE) ptr[idx] = excl + loc[i];
  }
  if (t == 1023) ptr[NNODE] = sd[1023];
}

__global__ __launch_bounds__(256) void k_fill(const int* __restrict__ dst, const int* __restrict__ ptr,
                                              int* __restrict__ fil, int* __restrict__ csr){
  int e = blockIdx.x*256 + threadIdx.x;
  if (e >= NEDGE) return;
  int d = dst[e];
  int pos = ptr[d] + atomicAdd(&fil[d], 1);
  csr[pos] = e;
}

// ------------------------- fused LSTM + temporal attention + static branch -------------------------
// block: 256 threads = 4 waves, 16 nodes/block (4 nodes/wave). lane j = hidden idx.
// STRUCTURAL register fix (R10): 8->4 nodes/thread halves acc+state regs (natural need ~80-100).
// Launch-bounds calibration: cap = 256/arg; (256,2)->128 cap, now ABOVE natural need -> no spill.
// History: 8 nodes/thread spilled at every cap: 790MB@64, 493MB@84, 351MB@128 (R5/R8/R10).
__global__ __launch_bounds__(256, 2) void k_lstm(
    const float* __restrict__ x,
    const float* __restrict__ Wih, const float* __restrict__ Whh,
    const float* __restrict__ bih, const float* __restrict__ bhh,
    const float* __restrict__ Wa,
    const float* __restrict__ Wn, const float* __restrict__ bnb,
    float* __restrict__ hnode)
{
  __shared__ float Xs[16][80];
  __shared__ float Hs[16][64];
  __shared__ float WcL[256][20];
  const int tid = threadIdx.x;
  const int j   = tid & 63;
  const int grp = tid >> 6;
  const int mb  = blockIdx.x * 16;

  const float bg0 = bih[j]     + bhh[j];
  const float bg1 = bih[64+j]  + bhh[64+j];
  const float bg2 = bih[128+j] + bhh[128+j];
  const float bg3 = bih[192+j] + bhh[192+j];

  float c[4]; float ht0[4], ht1[4], ht2[4];
  #pragma unroll
  for (int i=0;i<4;i++) c[i] = 0.f;

  #pragma unroll
  for (int t=0; t<3; ++t) {
    __syncthreads();
    for (int idx = tid; idx < 16*80; idx += 256) {
      int node = idx / 80, k = idx - node*80;
      Xs[node][k] = (k < RTDIM) ? x[(size_t)(mb+node)*XROW + NFEAT + t*RTDIM + k] : 0.f;
    }
    float a0[4],a1[4],a2[4],a3[4];
    #pragma unroll
    for (int i=0;i<4;i++){a0[i]=0.f;a1[i]=0.f;a2[i]=0.f;a3[i]=0.f;}

    // ---- Wih phase: k = 0..79 (padded) ----
    for (int kc=0; kc<80; kc+=16) {
      __syncthreads();
      {
        int g0 = tid >> 2, q = tid & 3;
        #pragma unroll
        for (int gp=0; gp<4; ++gp) {
          int gate = g0 + gp*64;
          int k0 = kc + q*4;
          float4 v;
          v.x = (k0+0 < RTDIM) ? Wih[gate*RTDIM + k0+0] : 0.f;
          v.y = (k0+1 < RTDIM) ? Wih[gate*RTDIM + k0+1] : 0.f;
          v.z = (k0+2 < RTDIM) ? Wih[gate*RTDIM + k0+2] : 0.f;
          v.w = (k0+3 < RTDIM) ? Wih[gate*RTDIM + k0+3] : 0.f;
          *(float4*)&WcL[gate][q*4] = v;
        }
      }
      __syncthreads();
      #pragma unroll
      for (int k4=0;k4<4;++k4){
        const float4 w0 = *(const float4*)&WcL[j][k4*4];
        const float4 w1 = *(const float4*)&WcL[64+j][k4*4];
        const float4 w2 = *(const float4*)&WcL[128+j][k4*4];
        const float4 w3 = *(const float4*)&WcL[192+j][k4*4];
        #pragma unroll
        for (int i=0;i<4;++i){
          const float4 xv = *(const float4*)&Xs[grp*4+i][kc + k4*4];
          a0[i]=fmaf(w0.x,xv.x,a0[i]); a0[i]=fmaf(w0.y,xv.y,a0[i]); a0[i]=fmaf(w0.z,xv.z,a0[i]); a0[i]=fmaf(w0.w,xv.w,a0[i]);
          a1[i]=fmaf(w1.x,xv.x,a1[i]); a1[i]=fmaf(w1.y,xv.y,a1[i]); a1[i]=fmaf(w1.z,xv.z,a1[i]); a1[i]=fmaf(w1.w,xv.w,a1[i]);
          a2[i]=fmaf(w2.x,xv.x,a2[i]); a2[i]=fmaf(w2.y,xv.y,a2[i]); a2[i]=fmaf(w2.z,xv.z,a2[i]); a2[i]=fmaf(w2.w,xv.w,a2[i]);
          a3[i]=fmaf(w3.x,xv.x,a3[i]); a3[i]=fmaf(w3.y,xv.y,a3[i]); a3[i]=fmaf(w3.z,xv.z,a3[i]); a3[i]=fmaf(w3.w,xv.w,a3[i]);
        }
      }
    }
    // ---- Whh phase (skip at t=0, h0 == 0) ----
    if (t > 0) {
      for (int kc=0; kc<64; kc+=16) {
        __syncthreads();
        {
          int g0 = tid >> 2, q = tid & 3;
          #pragma unroll
          for (int gp=0; gp<4; ++gp) {
            int gate = g0 + gp*64;
            *(float4*)&WcL[gate][q*4] = *(const float4*)&Whh[gate*64 + kc + q*4];
          }
        }
        __syncthreads();
        #pragma unroll
        for (int k4=0;k4<4;++k4){
          const float4 w0 = *(const float4*)&WcL[j][k4*4];
          const float4 w1 = *(const float4*)&WcL[64+j][k4*4];
          const float4 w2 = *(const float4*)&WcL[128+j][k4*4];
          const float4 w3 = *(const float4*)&WcL[192+j][k4*4];
          #pragma unroll
          for (int i=0;i<4;++i){
            const float4 xv = *(const float4*)&Hs[grp*4+i][kc + k4*4];
            a0[i]=fmaf(w0.x,xv.x,a0[i]); a0[i]=fmaf(w0.y,xv.y,a0[i]); a0[i]=fmaf(w0.z,xv.z,a0[i]); a0[i]=fmaf(w0.w,xv.w,a0[i]);
            a1[i]=fmaf(w1.x,xv.x,a1[i]); a1[i]=fmaf(w1.y,xv.y,a1[i]); a1[i]=fmaf(w1.z,xv.z,a1[i]); a1[i]=fmaf(w1.w,xv.w,a1[i]);
            a2[i]=fmaf(w2.x,xv.x,a2[i]); a2[i]=fmaf(w2.y,xv.y,a2[i]); a2[i]=fmaf(w2.z,xv.z,a2[i]); a2[i]=fmaf(w2.w,xv.w,a2[i]);
            a3[i]=fmaf(w3.x,xv.x,a3[i]); a3[i]=fmaf(w3.y,xv.y,a3[i]); a3[i]=fmaf(w3.z,xv.z,a3[i]); a3[i]=fmaf(w3.w,xv.w,a3[i]);
          }
        }
      }
    }
    __syncthreads();  // all Hs reads done before overwrite
    #pragma unroll
    for (int i=0;i<4;++i){
      float iv = fsig(a0[i]+bg0);
      float fv = fsig(a1[i]+bg1);
      float gv = ftanh(a2[i]+bg2);
      float ov = fsig(a3[i]+bg3);
      float cc = fv*c[i] + iv*gv;
      c[i] = cc;
      float hv = ov * ftanh(cc);
      if (t == 0) ht0[i] = hv;
      else if (t == 1) ht1[i] = hv;
      else ht2[i] = hv;
      if (t < 2) Hs[grp*4+i][j] = hv;
    }
  }

  // ---- temporal attention (softmax over T; ba cancels) ----
  const float wa = Wa[j];
  float htemp[4];
  #pragma unroll
  for (int i=0;i<4;++i){
    float s0 = ht0[i]*wa, s1 = ht1[i]*wa, s2 = ht2[i]*wa;
    #pragma unroll
    for (int off=32; off; off>>=1){
      s0 += __shfl_xor(s0, off);
      s1 += __shfl_xor(s1, off);
      s2 += __shfl_xor(s2, off);
    }
    float mx = fmaxf(s0, fmaxf(s1, s2));
    float e0 = __expf(s0-mx), e1 = __expf(s1-mx), e2 = __expf(s2-mx);
    float inv = __fdividef(1.f, e0+e1+e2);
    htemp[i] = (e0*ht0[i] + e1*ht1[i] + e2*ht2[i]) * inv;
  }

  // ---- static branch: relu(node_f @ Wn^T + bnb) ----
  __syncthreads();
  for (int idx = tid; idx < 16*64; idx += 256){
    int node = idx >> 6, k = idx & 63;
    Xs[node][k] = (k < NFEAT) ? x[(size_t)(mb+node)*XROW + k] : 0.f;
  }
  float as_[4];
  #pragma unroll
  for (int i=0;i<4;++i) as_[i]=0.f;
  for (int kc=0; kc<64; kc+=16){
    __syncthreads();
    {
      int g0 = tid >> 2, q = tid & 3;   // 64 gates in one pass
      int k0 = kc + q*4;
      float4 v;
      v.x = (k0+0 < NFEAT) ? Wn[g0*NFEAT + k0+0] : 0.f;
      v.y = (k0+1 < NFEAT) ? Wn[g0*NFEAT + k0+1] : 0.f;
      v.z = (k0+2 < NFEAT) ? Wn[g0*NFEAT + k0+2] : 0.f;
      v.w = (k0+3 < NFEAT) ? Wn[g0*NFEAT + k0+3] : 0.f;
      *(float4*)&WcL[g0][q*4] = v;
    }
    __syncthreads();
    #pragma unroll
    for (int k4=0;k4<4;++k4){
      const float4 w = *(const float4*)&WcL[j][k4*4];
      #pragma unroll
      for (int i=0;i<4;++i){
        const float4 xv = *(const float4*)&Xs[grp*4+i][kc + k4*4];
        as_[i]=fmaf(w.x,xv.x,as_[i]); as_[i]=fmaf(w.y,xv.y,as_[i]);
        as_[i]=fmaf(w.z,xv.z,as_[i]); as_[i]=fmaf(w.w,xv.w,as_[i]);
      }
    }
  }
  const float bn = bnb[j];
  #pragma unroll
  for (int i=0;i<4;++i){
    float hs = as_[i] + bn; hs = hs > 0.f ? hs : 0.f;
    hnode[(size_t)(mb+grp*4+i)*64 + j] = htemp[i] + hs;
  }
}

// ------------------------- xw = in @ W^T (+BN affine on load) + fused asrc/adst -------------------------
template<int K, bool AFF>
__global__ __launch_bounds__(256, 2) void k_xw(
    const float* __restrict__ in, const float* __restrict__ W,
    const float* __restrict__ avs, const float* __restrict__ avd,
    const float* __restrict__ affA, const float* __restrict__ affB,
    float* __restrict__ XW, float* __restrict__ asrc, float* __restrict__ adst)
{
  __shared__ float Xs[32][K];
  __shared__ float WcL[256][20];
  const int tid = threadIdx.x;
  const int j   = tid & 63;
  const int grp = tid >> 6;
  const int mb  = blockIdx.x * 32;

  if constexpr (K == 256) {
    float sA = AFF ? affA[tid] : 1.f;
    float sB = AFF ? affB[tid] : 0.f;
    for (int node=0; node<32; ++node){
      float v = in[(size_t)(mb+node)*K + tid];
      Xs[node][tid] = v*sA + sB;
    }
  } else {
    for (int idx = tid; idx < 32*K; idx += 256){
      int node = idx / K, k = idx - node*K;
      Xs[node][k] = in[(size_t)(mb+node)*K + k];
    }
  }

  float a0[8],a1[8],a2[8],a3[8];
  #pragma unroll
  for (int i=0;i<8;i++){a0[i]=0.f;a1[i]=0.f;a2[i]=0.f;a3[i]=0.f;}

  for (int kc=0; kc<K; kc+=16){
    __syncthreads();
    {
      int g0 = tid >> 2, q = tid & 3;
      #pragma unroll
      for (int gp=0;gp<4;++gp){
        int gate = g0 + gp*64;
        *(float4*)&WcL[gate][q*4] = *(const float4*)&W[(size_t)gate*K + kc + q*4];
      }
    }
    __syncthreads();
    #pragma unroll
    for (int k4=0;k4<4;++k4){
      const float4 w0 = *(const float4*)&WcL[j][k4*4];
      const float4 w1 = *(const float4*)&WcL[64+j][k4*4];
      const float4 w2 = *(const float4*)&WcL[128+j][k4*4];
      const float4 w3 = *(const float4*)&WcL[192+j][k4*4];
      #pragma unroll
      for (int i=0;i<8;++i){
        const float4 xv = *(const float4*)&Xs[grp*8+i][kc + k4*4];
        a0[i]=fmaf(w0.x,xv.x,a0[i]); a0[i]=fmaf(w0.y,xv.y,a0[i]); a0[i]=fmaf(w0.z,xv.z,a0[i]); a0[i]=fmaf(w0.w,xv.w,a0[i]);
        a1[i]=fmaf(w1.x,xv.x,a1[i]); a1[i]=fmaf(w1.y,xv.y,a1[i]); a1[i]=fmaf(w1.z,xv.z,a1[i]); a1[i]=fmaf(w1.w,xv.w,a1[i]);
        a2[i]=fmaf(w2.x,xv.x,a2[i]); a2[i]=fmaf(w2.y,xv.y,a2[i]); a2[i]=fmaf(w2.z,xv.z,a2[i]); a2[i]=fmaf(w2.w,xv.w,a2[i]);
        a3[i]=fmaf(w3.x,xv.x,a3[i]); a3[i]=fmaf(w3.y,xv.y,a3[i]); a3[i]=fmaf(w3.z,xv.z,a3[i]); a3[i]=fmaf(w3.w,xv.w,a3[i]);
      }
    }
  }

  #pragma unroll
  for (int i=0;i<8;++i){
    size_t base = (size_t)(mb+grp*8+i)*256;
    XW[base + j]       = a0[i];
    XW[base + 64 + j]  = a1[i];
    XW[base + 128 + j] = a2[i];
    XW[base + 192 + j] = a3[i];
  }
  const float s0w = avs[j], s1w = avs[64+j], s2w = avs[128+j], s3w = avs[192+j];
  const float d0w = avd[j], d1w = avd[64+j], d2w = avd[128+j], d3w = avd[192+j];
  #pragma unroll
  for (int i=0;i<8;++i){
    float ps0=a0[i]*s0w, ps1=a1[i]*s1w, ps2=a2[i]*s2w, ps3=a3[i]*s3w;
    float pd0=a0[i]*d0w, pd1=a1[i]*d1w, pd2=a2[i]*d2w, pd3=a3[i]*d3w;
    #pragma unroll
    for (int off=32; off; off>>=1){
      ps0 += __shfl_xor(ps0, off); ps1 += __shfl_xor(ps1, off);
      ps2 += __shfl_xor(ps2, off); ps3 += __shfl_xor(ps3, off);
      pd0 += __shfl_xor(pd0, off); pd1 += __shfl_xor(pd1, off);
      pd2 += __shfl_xor(pd2, off); pd3 += __shfl_xor(pd3, off);
    }
    if (j == 0){
      int m = mb + grp*8 + i;
      asrc[m*4+0]=ps0; asrc[m*4+1]=ps1; asrc[m*4+2]=ps2; asrc[m*4+3]=ps3;
      adst[m*4+0]=pd0; adst[m*4+1]=pd1; adst[m*4+2]=pd2; adst[m*4+3]=pd3;
    }
  }
}

// ------------------------- per-dst softmax stats (max & denom incl. self loop) -------------------------
__global__ __launch_bounds__(256) void k_stats(
    const float* __restrict__ asrc, const float* __restrict__ adst,
    const int* __restrict__ esrc, const int* __restrict__ csr, const int* __restrict__ ptr,
    float* __restrict__ emax, float* __restrict__ den)
{
  const int m = blockIdx.x*4 + (threadIdx.x>>6);
  const int lane = threadIdx.x & 63;
  const int n = m % NNODE;
  const int bb = m / NNODE;
  const int s0 = ptr[n], s1 = ptr[n+1];
  const float4 ad  = *(const float4*)&adst[(size_t)m*4];
  const float4 asf = *(const float4*)&asrc[(size_t)m*4];
  const float ex0 = lrelu(asf.x+ad.x), ex1 = lrelu(asf.y+ad.y);
  const float ex2 = lrelu(asf.z+ad.z), ex3 = lrelu(asf.w+ad.w);
  float m0=ex0, m1=ex1, m2=ex2, m3=ex3;
  for (int e = s0+lane; e < s1; e += 64){
    int src = esrc[csr[e]];
    const float4 av = *(const float4*)&asrc[(size_t)(bb*NNODE+src)*4];
    m0 = fmaxf(m0, lrelu(av.x+ad.x));
    m1 = fmaxf(m1, lrelu(av.y+ad.y));
    m2 = fmaxf(m2, lrelu(av.z+ad.z));
    m3 = fmaxf(m3, lrelu(av.w+ad.w));
  }
  #pragma unroll
  for (int off=32; off; off>>=1){
    m0 = fmaxf(m0, __shfl_xor(m0, off));
    m1 = fmaxf(m1, __shfl_xor(m1, off));
    m2 = fmaxf(m2, __shfl_xor(m2, off));
    m3 = fmaxf(m3, __shfl_xor(m3, off));
  }
  float d0=0.f,d1=0.f,d2=0.f,d3=0.f;
  for (int e = s0+lane; e < s1; e += 64){
    int src = esrc[csr[e]];
    const float4 av = *(const float4*)&asrc[(size_t)(bb*NNODE+src)*4];
    d0 += __expf(lrelu(av.x+ad.x) - m0);
    d1 += __expf(lrelu(av.y+ad.y) - m1);
    d2 += __expf(lrelu(av.z+ad.z) - m2);
    d3 += __expf(lrelu(av.w+ad.w) - m3);
  }
  #pragma unroll
  for (int off=32; off; off>>=1){
    d0 += __shfl_xor(d0, off); d1 += __shfl_xor(d1, off);
    d2 += __shfl_xor(d2, off); d3 += __shfl_xor(d3, off);
  }
  d0 += __expf(ex0 - m0); d1 += __expf(ex1 - m1);
  d2 += __expf(ex2 - m2); d3 += __expf(ex3 - m3);
  if (lane == 0){
    float4 mv = {m0,m1,m2,m3}; *(float4*)&emax[(size_t)m*4] = mv;
    float4 dv = {d0,d1,d2,d3}; *(float4*)&den[(size_t)m*4]  = dv;
  }
}

// ------------------------- per-dst weighted aggregation + bias + relu -------------------------
__global__ __launch_bounds__(256) void k_agg(
    const float* __restrict__ XW, const float* __restrict__ asrc, const float* __restrict__ adst,
    const float* __restrict__ emax, const float* __restrict__ den,
    const int* __restrict__ esrc, const int* __restrict__ csr, const int* __restrict__ ptr,
    const float* __restrict__ bias, float* __restrict__ out)
{
  const int m = blockIdx.x*4 + (threadIdx.x>>6);
  const int lane = threadIdx.x & 63;
  const int h = lane >> 4;
  const int n = m % NNODE;
  const int bb = m / NNODE;
  const float adh  = adst[(size_t)m*4 + h];
  const float mxh  = emax[(size_t)m*4 + h];
  const float invd = __fdividef(1.f, den[(size_t)m*4 + h] + 1e-16f);
  float al = __expf(lrelu(asrc[(size_t)m*4+h] + adh) - mxh) * invd;
  float4 xv = *(const float4*)&XW[(size_t)m*256 + lane*4];
  float acx = al*xv.x, acy = al*xv.y, acz = al*xv.z, acw = al*xv.w;
  const int s0 = ptr[n], s1 = ptr[n+1];
  for (int e = s0; e < s1; ++e){
    int src = esrc[csr[e]];
    int ms = bb*NNODE + src;
    float a2 = __expf(lrelu(asrc[(size_t)ms*4+h] + adh) - mxh) * invd;
    float4 x2 = *(const float4*)&XW[(size_t)ms*256 + lane*4];
    acx = fmaf(a2, x2.x, acx); acy = fmaf(a2, x2.y, acy);
    acz = fmaf(a2, x2.z, acz); acw = fmaf(a2, x2.w, acw);
  }
  const float4 bv = *(const float4*)&bias[lane*4];
  acx = fmaxf(acx+bv.x, 0.f); acy = fmaxf(acy+bv.y, 0.f);
  acz = fmaxf(acz+bv.z, 0.f); acw = fmaxf(acw+bv.w, 0.f);
  float4 o = {acx,acy,acz,acw};
  *(float4*)&out[(size_t)m*256 + lane*4] = o;
}

// ------------------------- batchnorm -------------------------
__global__ __launch_bounds__(256) void k_bnstats(const float* __restrict__ H,
                                                 float* __restrict__ sum, float* __restrict__ sq){
  int c = threadIdx.x;
  float s = 0.f, q = 0.f;
  for (int r = blockIdx.x; r < MTOT; r += gridDim.x){
    float v = H[(size_t)r*256 + c];
    s += v; q += v*v;
  }
  atomicAdd(&sum[c], s);
  atomicAdd(&sq[c],  q);
}

__global__ __launch_bounds__(256) void k_bnfin(const float* __restrict__ sum, const float* __restrict__ sq,
    const float* __restrict__ g, const float* __restrict__ be,
    float* __restrict__ a, float* __restrict__ bsh)
{
  int c = threadIdx.x;
  float mean = sum[c] * (1.f/MTOT);
  float var  = sq[c]  * (1.f/MTOT) - mean*mean;
  float rstd = rsqrtf(var + BNEPS);
  float av = g[c] * rstd;
  a[c]   = av;
  bsh[c] = be[c] - mean*av;
}

__global__ __launch_bounds__(256) void k_fold(const float* __restrict__ a2, const float* __restrict__ b2s,
    const float* __restrict__ Wcw, const float* __restrict__ bc,
    float* __restrict__ wcp, float* __restrict__ bias0)
{
  __shared__ float red[256];
  int c = threadIdx.x;
  float w = Wcw[c];
  wcp[c] = a2[c]*w;
  red[c] = b2s[c]*w;
  __syncthreads();
  for (int off=128; off; off>>=1){
    if (c < off) red[c] += red[c+off];
    __syncthreads();
  }
  if (c == 0) bias0[0] = red[0] + bc[0];
}

// ------------------------- final projection -------------------------
__global__ __launch_bounds__(256) void k_out(const float* __restrict__ H, const float* __restrict__ wcp,
    const float* __restrict__ bias0, float* __restrict__ out)
{
  const int m = blockIdx.x*4 + (threadIdx.x>>6);
  const int lane = threadIdx.x & 63;
  const float4 h4 = *(const float4*)&H[(size_t)m*256 + lane*4];
  const float4 w4 = *(const float4*)&wcp[lane*4];
  float p = h4.x*w4.x + h4.y*w4.y + h4.z*w4.z + h4.w*w4.w;
  #pragma unroll
  for (int off=32; off; off>>=1) p += __shfl_xor(p, off);
  if (lane == 0) out[m] = p + bias0[0];
}

// ------------------------- launch -------------------------
extern "C" void kernel_launch(void* const* d_in, const int* in_sizes, int n_in,
                              void* d_out, int out_size, void* d_ws, size_t ws_size,
                              hipStream_t stream)
{
  const float* x    = (const float*)d_in[0];
  const int*   ei   = (const int*)d_in[1];
  const float* Wih  = (const float*)d_in[2];
  const float* Whh  = (const float*)d_in[3];
  const float* bih  = (const float*)d_in[4];
  const float* bhh  = (const float*)d_in[5];
  const float* Wa   = (const float*)d_in[6];
  const float* Wn   = (const float*)d_in[8];
  const float* bnb  = (const float*)d_in[9];
  const float* W1   = (const float*)d_in[10];
  const float* as1  = (const float*)d_in[11];
  const float* ad1  = (const float*)d_in[12];
  const float* b1   = (const float*)d_in[13];
  const float* W2   = (const float*)d_in[14];
  const float* as2  = (const float*)d_in[15];
  const float* ad2  = (const float*)d_in[16];
  const float* b2   = (const float*)d_in[17];
  const float* g1   = (const float*)d_in[18];
  const float* be1  = (const float*)d_in[19];
  const float* g2   = (const float*)d_in[20];
  const float* be2  = (const float*)d_in[21];
  const float* Wcw  = (const float*)d_in[22];
  const float* bc   = (const float*)d_in[23];

  float* ws    = (float*)d_ws;
  float* hnode = ws + OFF_HN;
  float* XW    = ws + OFF_XW;
  float* H2    = ws + OFF_H2;
  float* asrc  = ws + OFF_ASRC;
  float* adst  = ws + OFF_ADST;
  float* emax  = ws + OFF_EMAX;
  float* den   = ws + OFF_DEN;
  float* sum1  = ws + OFF_STAT;
  float* sq1   = sum1 + 256;
  float* sum2  = sq1 + 256;
  float* sq2   = sum2 + 256;
  float* aff   = ws + OFF_AFF;
  float* A1 = aff, *B1s = aff+256, *A2 = aff+512, *B2s = aff+768, *WCP = aff+1024, *BIAS0 = aff+1280;
  int* cnt = (int*)(ws + OFF_INT);
  int* fil = cnt + NNODE;
  int* ptr = fil + NNODE;
  int* csr = ptr + NNODE + 1;

  const int* esrc = ei;
  const int* edst = ei + NEDGE;

  k_zero<<<dim3((2*NNODE+255)/256), dim3(256), 0, stream>>>((float*)cnt, 2*NNODE);
  k_zero<<<dim3(4), dim3(256), 0, stream>>>(sum1, 1024);
  k_count<<<dim3((NEDGE+255)/256), dim3(256), 0, stream>>>(edst, cnt);
  k_scan<<<dim3(1), dim3(1024), 0, stream>>>(cnt, ptr);
  k_fill<<<dim3((NEDGE+255)/256), dim3(256), 0, stream>>>(edst, ptr, fil, csr);

  k_lstm<<<dim3(MTOT/16), dim3(256), 0, stream>>>(x, Wih, Whh, bih, bhh, Wa, Wn, bnb, hnode);

  k_xw<64,false><<<dim3(MTOT/32), dim3(256), 0, stream>>>(hnode, W1, as1, ad1,
      (const float*)nullptr, (const float*)nullptr, XW, asrc, adst);
  k_stats<<<dim3(MTOT/4), dim3(256), 0, stream>>>(asrc, adst, esrc, csr, ptr, emax, den);
  k_agg<<<dim3(MTOT/4), dim3(256), 0, stream>>>(XW, asrc, adst, emax, den, esrc, csr, ptr, b1, H2);
  k_bnstats<<<dim3(256), dim3(256), 0, stream>>>(H2, sum1, sq1);
  k_bnfin<<<dim3(1), dim3(256), 0, stream>>>(sum1, sq1, g1, be1, A1, B1s);

  k_xw<256,true><<<dim3(MTOT/32), dim3(256), 0, stream>>>(H2, W2, as2, ad2, A1, B1s, XW, asrc, adst);
  k_stats<<<dim3(MTOT/4), dim3(256), 0, stream>>>(asrc, adst, esrc, csr, ptr, emax, den);
  k_agg<<<dim3(MTOT/4), dim3(256), 0, stream>>>(XW, asrc, adst, emax, den, esrc, csr, ptr, b2, H2);
  k_bnstats<<<dim3(256), dim3(256), 0, stream>>>(H2, sum2, sq2);
  k_bnfin<<<dim3(1), dim3(256), 0, stream>>>(sum2, sq2, g2, be2, A2, B2s);
  k_fold<<<dim3(1), dim3(256), 0, stream>>>(A2, B2s, Wcw, bc, WCP, BIAS0);

  k_out<<<dim3(MTOT/4), dim3(256), 0, stream>>>(H2, WCP, BIAS0, (float*)d_out);
}